// Round 6
// baseline (261.472 us; speedup 1.0000x reference)
//
#include <hip/hip_runtime.h>
#include <math.h>

#define LNB      32
#define NODE_IN  128
#define EDGE_IN  64
#define TIME_D   128
#define D_MODEL  320
#define N_HEAD   8
#define D_K      64
#define NHD      512
#define HID      128
#define IN2      448
#define N_DSTN   8192

typedef __attribute__((ext_vector_type(8))) short bf16x8;
typedef __attribute__((ext_vector_type(4))) float f32x4;
#define MFMA16(a,b,c) __builtin_amdgcn_mfma_f32_16x16x32_bf16(a,b,c,0,0,0)

// ---- ws layout (elements of unsigned short) ----
#define WS_QKM   0            // 8192*2560 : qk (h-major) -> mbar (d*8+h layout), in place
#define WS_WQK   20971520     // 2560*128  : folded wk@wq   (row-major [h*320+d][k])
#define WS_WVF   21299200     // 320*2560  : folded fcw@wv  ([c][d*8+h])
#define WS_NWC   22118400     // 128*448   : [nw1 | nw2*lng]
#define WS_F32   22175744     // 3520 floats
#define WS_X     22182784     // 8192*320 f32 x buffer (plain stores, full-K blocks)
// total = 27,425,664 shorts = 54.9 MB

#define F_C0     0            // 512
#define F_C0K    512          // 2560
#define F_CC     3072         // 320 : fcb + q-const residual
#define F_B2     3392         // 128 : nb + nw2@lnb

// native RTNE f32->bf16 (v_cvt_pk_bf16_f32 on gfx950) — bit-identical to manual RTNE
__device__ __forceinline__ unsigned short f2bf(float f) {
  __bf16 h = (__bf16)f;
  return __builtin_bit_cast(unsigned short, h);
}
__device__ __forceinline__ bf16x8 pack8(const float* v) {
  unsigned short b8[8];
  #pragma unroll
  for (int j = 0; j < 8; ++j) b8[j] = f2bf(v[j]);
  return *(const bf16x8*)b8;
}

// async global->LDS, 16 B per lane; LDS dest = wave-uniform base + lane*16
#define GLDS(srcp, dstp) __builtin_amdgcn_global_load_lds(                     \
    (const __attribute__((address_space(1))) unsigned int*)(const void*)(srcp),\
    (__attribute__((address_space(3))) unsigned int*)(void*)(dstp), 16, 0, 0)

// =================== prep_all: 4 independent preps, one launch ==============
// blocks [0,226): prep1a  | [226,386): prep1b | [386,466): wqk | [466,1266): wvf
__global__ __launch_bounds__(256)
void prep_all(const float* __restrict__ nw, const float* __restrict__ lng,
              const float* __restrict__ fcb, const float* __restrict__ ph,
              const float* __restrict__ wq, const float* __restrict__ lnb_,
              const float* __restrict__ nb, const float* __restrict__ wk,
              const float* __restrict__ fcw, const float* __restrict__ wv,
              unsigned short* __restrict__ ws)
{
  __shared__ float smem[10240];          // 40 KB union
  const int b = blockIdx.x, tid = threadIdx.x;
  unsigned short* nwc = ws + WS_NWC;
  float* f32r = (float*)(ws + WS_F32);

  if (b < 226) {                         // ---- prep1a: elementwise folds ----
    int i = b * 256 + tid;
    if (i < 16384) {                     // nw1 cast
      int o = i >> 7, k = i & 127;
      nwc[o * IN2 + k] = f2bf(nw[(size_t)o * IN2 + k]);
    } else if (i < 57344) {              // nw2g = nw2 * lng
      int j = i - 16384, o = j / 320, c = j - o * 320;
      nwc[o * IN2 + 128 + c] = f2bf(nw[(size_t)o * IN2 + 128 + c] * lng[c]);
    } else if (i < 57664) {              // cc[c] = fcb + q-const
      int c = i - 57344;
      f32r[F_CC + c] = fcb[c] + (c >= 192 ? __cosf(ph[c - 192]) : 0.f);
    }
  } else if (b < 386) {                  // ---- prep1b: c0 + b2 ----
    int gw = ((b - 226) * 256 + tid) >> 6;
    int ln = tid & 63;
    if (gw < 512) {                      // c0[j] = cos(ph) . wq[j][192:]
      float s = __cosf(ph[ln])      * wq[(size_t)gw * D_MODEL + 192 + ln]
              + __cosf(ph[ln + 64]) * wq[(size_t)gw * D_MODEL + 256 + ln];
      #pragma unroll
      for (int off = 32; off >= 1; off >>= 1) s += __shfl_xor(s, off);
      if (ln == 0) f32r[F_C0 + gw] = s;
    } else {                             // b2[o] = nb + nw2 . lnb
      int o = gw - 512;
      float s = 0.f;
      #pragma unroll
      for (int k = 0; k < 5; ++k) {
        int c = ln + 64 * k;
        s += nw[(size_t)o * IN2 + 128 + c] * lnb_[c];
      }
      #pragma unroll
      for (int off = 32; off >= 1; off >>= 1) s += __shfl_xor(s, off);
      if (ln == 0) f32r[F_B2 + o] = nb[o] + s;
    }
  } else if (b < 466) {                  // ---- prep_wqk fold ----
    float* sQw = smem;                   // 64*128
    float* sKw = smem + 8192;            // 64*32
    int bw = b - 386;
    int h = bw / 10, d0 = (bw - h * 10) * 32;
    #pragma unroll 4
    for (int it = 0; it < 32; ++it) {
      int idx = it * 256 + tid;
      int r = idx >> 7, c = idx & 127;
      sQw[idx] = wq[(size_t)(h * 64 + r) * D_MODEL + c];
    }
    #pragma unroll
    for (int it = 0; it < 8; ++it) {
      int idx = it * 256 + tid;
      int r = idx >> 5, c = idx & 31;
      sKw[idx] = wk[(size_t)(h * 64 + r) * D_MODEL + d0 + c];
    }
    __syncthreads();
    int di = tid >> 3, k0 = (tid & 7) * 16;
    float acc[16] = {};
    for (int dk = 0; dk < 64; ++dk) {
      float w = sKw[dk * 32 + di];
      #pragma unroll
      for (int j = 0; j < 16; ++j) acc[j] += w * sQw[dk * 128 + k0 + j];
    }
    unsigned short* dst = ws + WS_WQK + (size_t)(h * 320 + d0 + di) * 128 + k0;
    #pragma unroll
    for (int j = 0; j < 16; ++j) dst[j] = f2bf(acc[j]);
  } else {                               // ---- prep_wvf fold ----
    float* sF = smem;                    // 32*64
    float* sW = smem + 2048;             // 64*32
    int bb = b - 466;
    int h = bb / 100, r2 = bb - h * 100;
    int ct = r2 / 10;
    int c0 = ct * 32, d0 = (r2 - ct * 10) * 32;
    #pragma unroll
    for (int it = 0; it < 8; ++it) {
      int idx = it * 256 + tid;
      int i = idx >> 6, jj = idx & 63;
      sF[idx] = fcw[(size_t)(c0 + i) * NHD + h * 64 + jj];
    }
    #pragma unroll
    for (int it = 0; it < 8; ++it) {
      int idx = it * 256 + tid;
      int jj = idx >> 5, i = idx & 31;
      sW[idx] = wv[(size_t)(h * 64 + jj) * D_MODEL + d0 + i];
    }
    __syncthreads();
    int ci = tid >> 3, dj0 = (tid & 7) * 4;
    float acc[4] = {};
    for (int jj = 0; jj < 64; ++jj) {
      float f = sF[ci * 64 + jj];
      #pragma unroll
      for (int k = 0; k < 4; ++k) acc[k] += f * sW[jj * 32 + dj0 + k];
    }
    unsigned short* wvf = ws + WS_WVF;
    #pragma unroll
    for (int k = 0; k < 4; ++k)
      wvf[(size_t)(c0 + ci) * 2560 + (size_t)(d0 + dj0 + k) * 8 + h] = f2bf(acc[k]);
  }
}

// =================== prep_c0k: one wave per hd ==============================
__global__ __launch_bounds__(256)
void prep_c0k(const float* __restrict__ wk, unsigned short* __restrict__ ws)
{
  float* f32r = (float*)(ws + WS_F32);
  int gw = (blockIdx.x * 256 + threadIdx.x) >> 6;   // 0..2559
  int ln = threadIdx.x & 63;
  int h = gw / 320, d = gw - h * 320;
  float s = f32r[F_C0 + h * 64 + ln] * wk[(size_t)(h * 64 + ln) * D_MODEL + d];
  #pragma unroll
  for (int off = 32; off >= 1; off >>= 1) s += __shfl_xor(s, off);
  if (ln == 0) f32r[F_C0K + gw] = s;
}

// =================== K1: qk = nf @ wqk^T + c0k  (h-major layout) ============
__global__ __launch_bounds__(256, 6)
void tgat_qk(const float* __restrict__ nf, const unsigned short* __restrict__ ws,
             unsigned short* __restrict__ qkm)
{
  __shared__ alignas(16) unsigned short sA[64 * 136];
  const int tid = threadIdx.x, wid = tid >> 6, lane = tid & 63, qd = lane >> 4, lm = lane & 15;
  const int mt_blk = blockIdx.x / 20, nt_blk = blockIdx.x - mt_blk * 20;
  const int n0 = mt_blk * 64, c0 = nt_blk * 128;
  const unsigned short* wqk = ws + WS_WQK;
  const float* f32r = (const float*)(ws + WS_F32);

  { // stage A: 64 x 128 bf16 (coalesced)
    int n = tid >> 2, k0 = (tid & 3) * 32;
    const float4* src = (const float4*)(nf + (size_t)(n0 + n) * NODE_IN + k0);
    #pragma unroll
    for (int q = 0; q < 4; ++q) {
      float4 f0 = src[2 * q], f1 = src[2 * q + 1];
      float v[8] = {f0.x, f0.y, f0.z, f0.w, f1.x, f1.y, f1.z, f1.w};
      *(bf16x8*)&sA[n * 136 + k0 + q * 8] = pack8(v);
    }
  }
  __syncthreads();

  f32x4 acc[2][4] = {};
  for (int kt = 0; kt < 4; ++kt) {
    bf16x8 a[4];
    #pragma unroll
    for (int mt = 0; mt < 4; ++mt)
      a[mt] = *(const bf16x8*)&sA[(mt * 16 + lm) * 136 + kt * 32 + qd * 8];
    #pragma unroll
    for (int t = 0; t < 2; ++t) {
      int cg = c0 + (2 * wid + t) * 16 + lm;
      bf16x8 b = *(const bf16x8*)&wqk[(size_t)cg * 128 + kt * 32 + qd * 8];
      #pragma unroll
      for (int mt = 0; mt < 4; ++mt) acc[t][mt] = MFMA16(a[mt], b, acc[t][mt]);
    }
  }
  #pragma unroll
  for (int t = 0; t < 2; ++t) {
    int cg = c0 + (2 * wid + t) * 16 + lm;
    float ck = f32r[F_C0K + cg];
    #pragma unroll
    for (int mt = 0; mt < 4; ++mt)
      #pragma unroll
      for (int r = 0; r < 4; ++r)
        qkm[(size_t)(n0 + mt * 16 + qd * 4 + r) * 2560 + cg] = f2bf(acc[t][mt][r] + ck);
  }
}

// =================== K2: attention (scores ∥ m-build, ONE barrier) ==========
// Wave 0 computes scores from DIRECT operands (nf/ef per-lane gathers, te in
// registers, qfrag from global) — no LDS dependency, starts immediately.
// Waves 1-3 concurrently build sM (needed only for the mbar transpose).
// One barrier (sM + sATT ready), then all 4 waves do 5 mbar tiles each.
__global__ __launch_bounds__(256, 5)
void tgat_attn(const float* __restrict__ nf, const float* __restrict__ ef,
               const float* __restrict__ dtp, const int* __restrict__ nidx,
               const float* __restrict__ freq, const float* __restrict__ ph,
               unsigned short* __restrict__ qkm)
{
  __shared__ alignas(16) unsigned short sM[LNB * 328];    // 21 KB
  __shared__ alignas(16) unsigned short sATT[16 * 40];    // 1.25 KB

  const int tid = threadIdx.x;
  const int wid = tid >> 6, lane = tid & 63, qd = lane >> 4, lm = lane & 15;
  const int n = blockIdx.x;
  unsigned short* qn = qkm + (size_t)n * 2560;

  if (wid == 0) {
    // ---- scores: D[l][h] = m @ qk^T / 8 — direct operands, no barrier ----
    const int ni0 = nidx[n * 16 + (lm >> 1)];
    const int ni1 = nidx[n * 16 + 8 + (lm >> 1)];
    const float dt0 = dtp[(size_t)n * LNB + lm];
    const float dt1 = dtp[(size_t)n * LNB + 16 + lm];
    f32x4 acc0 = {}, acc1 = {};
    #pragma unroll
    for (int kt = 0; kt < 4; ++kt) {           // nf part
      bf16x8 qf = (bf16x8){0,0,0,0,0,0,0,0};
      if (lm < 8) qf = *(const bf16x8*)&qn[lm * 320 + kt * 32 + qd * 8];
      const int d0 = kt * 32 + qd * 8;
      const float4* s0 = (const float4*)(nf + (size_t)ni0 * NODE_IN + d0);
      const float4* s1 = (const float4*)(nf + (size_t)ni1 * NODE_IN + d0);
      float4 a = s0[0], b = s0[1], c = s1[0], d = s1[1];
      float v0[8] = {a.x,a.y,a.z,a.w,b.x,b.y,b.z,b.w};
      float v1[8] = {c.x,c.y,c.z,c.w,d.x,d.y,d.z,d.w};
      acc0 = MFMA16(pack8(v0), qf, acc0);
      acc1 = MFMA16(pack8(v1), qf, acc1);
    }
    #pragma unroll
    for (int kt = 4; kt < 6; ++kt) {           // ef part
      bf16x8 qf = (bf16x8){0,0,0,0,0,0,0,0};
      if (lm < 8) qf = *(const bf16x8*)&qn[lm * 320 + kt * 32 + qd * 8];
      const int e0 = kt * 32 + qd * 8 - 128;
      const float4* s0 = (const float4*)(ef + ((size_t)n * LNB + lm) * EDGE_IN + e0);
      const float4* s1 = (const float4*)(ef + ((size_t)n * LNB + 16 + lm) * EDGE_IN + e0);
      float4 a = s0[0], b = s0[1], c = s1[0], d = s1[1];
      float v0[8] = {a.x,a.y,a.z,a.w,b.x,b.y,b.z,b.w};
      float v1[8] = {c.x,c.y,c.z,c.w,d.x,d.y,d.z,d.w};
      acc0 = MFMA16(pack8(v0), qf, acc0);
      acc1 = MFMA16(pack8(v1), qf, acc1);
    }
    #pragma unroll
    for (int kt = 6; kt < 10; ++kt) {          // te part (in-register cos)
      bf16x8 qf = (bf16x8){0,0,0,0,0,0,0,0};
      if (lm < 8) qf = *(const bf16x8*)&qn[lm * 320 + kt * 32 + qd * 8];
      const int dd = kt * 32 + qd * 8 - 192;
      const float4* fq = (const float4*)(freq + dd);
      const float4* pp = (const float4*)(ph + dd);
      float4 f0 = fq[0], f1 = fq[1], p0 = pp[0], p1 = pp[1];
      float v0[8] = {__cosf(dt0*f0.x+p0.x), __cosf(dt0*f0.y+p0.y),
                     __cosf(dt0*f0.z+p0.z), __cosf(dt0*f0.w+p0.w),
                     __cosf(dt0*f1.x+p1.x), __cosf(dt0*f1.y+p1.y),
                     __cosf(dt0*f1.z+p1.z), __cosf(dt0*f1.w+p1.w)};
      float v1[8] = {__cosf(dt1*f0.x+p0.x), __cosf(dt1*f0.y+p0.y),
                     __cosf(dt1*f0.z+p0.z), __cosf(dt1*f0.w+p0.w),
                     __cosf(dt1*f1.x+p1.x), __cosf(dt1*f1.y+p1.y),
                     __cosf(dt1*f1.z+p1.z), __cosf(dt1*f1.w+p1.w)};
      acc0 = MFMA16(pack8(v0), qf, acc0);
      acc1 = MFMA16(pack8(v1), qf, acc1);
    }
    // softmax over 32 l per (h=lm) column pair
    float s[8], e[8];
    #pragma unroll
    for (int r = 0; r < 4; ++r) { s[r] = acc0[r] * 0.125f; s[4 + r] = acc1[r] * 0.125f; }
    float mx = s[0];
    #pragma unroll
    for (int i = 1; i < 8; ++i) mx = fmaxf(mx, s[i]);
    mx = fmaxf(mx, __shfl_xor(mx, 16));
    mx = fmaxf(mx, __shfl_xor(mx, 32));
    float sum = 0.f;
    #pragma unroll
    for (int i = 0; i < 8; ++i) { e[i] = __expf(s[i] - mx); sum += e[i]; }
    sum += __shfl_xor(sum, 16);
    sum += __shfl_xor(sum, 32);
    float inv = 1.f / sum;
    #pragma unroll
    for (int i = 0; i < 8; ++i) {
      int l = (i < 4) ? (qd * 4 + i) : (16 + qd * 4 + (i - 4));
      sATT[lm * 40 + l] = f2bf(e[i] * inv);
    }
  } else {
    // ---- waves 1-3: build sM (1280 items over 192 threads, 7 rounds) ----
    const int t3 = tid - 64;
    #pragma unroll 1
    for (int it = 0; it < 7; ++it) {
      int g = it * 192 + t3;
      if (g < 1280) {                    // wave-uniform at the tail
        int l = g & 31, dg = g >> 5;
        int d0 = dg * 8;
        float v[8];
        if (dg < 16) {
          int ni = nidx[n * 16 + (l >> 1)];
          const float4* src = (const float4*)(nf + (size_t)ni * NODE_IN + d0);
          float4 f0 = src[0], f1 = src[1];
          v[0]=f0.x; v[1]=f0.y; v[2]=f0.z; v[3]=f0.w; v[4]=f1.x; v[5]=f1.y; v[6]=f1.z; v[7]=f1.w;
        } else if (dg < 24) {
          const float4* src = (const float4*)(ef + ((size_t)n * LNB + l) * EDGE_IN + (d0 - NODE_IN));
          float4 f0 = src[0], f1 = src[1];
          v[0]=f0.x; v[1]=f0.y; v[2]=f0.z; v[3]=f0.w; v[4]=f1.x; v[5]=f1.y; v[6]=f1.z; v[7]=f1.w;
        } else {
          int dd = d0 - 192;
          float dt = dtp[(size_t)n * LNB + l];
          const float4* fq = (const float4*)(freq + dd);
          const float4* pp = (const float4*)(ph + dd);
          float4 q0 = fq[0], q1 = fq[1], p0 = pp[0], p1 = pp[1];
          v[0] = __cosf(dt * q0.x + p0.x); v[1] = __cosf(dt * q0.y + p0.y);
          v[2] = __cosf(dt * q0.z + p0.z); v[3] = __cosf(dt * q0.w + p0.w);
          v[4] = __cosf(dt * q1.x + p1.x); v[5] = __cosf(dt * q1.y + p1.y);
          v[6] = __cosf(dt * q1.z + p1.z); v[7] = __cosf(dt * q1.w + p1.w);
        }
        *(bf16x8*)&sM[l * 328 + d0] = pack8(v);
      }
    }
  }
  __syncthreads();                       // single barrier: sM + sATT ready

  // ---- mbar: 20 d-tiles, 5 per wave; A = m^T via transposed LDS reads ----
  bf16x8 batt = *(const bf16x8*)&sATT[lm * 40 + qd * 8];
  #pragma unroll
  for (int u = 0; u < 5; ++u) {
    const int dtile = wid * 5 + u;
    const int d = dtile * 16 + lm;
    unsigned short a8[8];
    #pragma unroll
    for (int j = 0; j < 8; ++j) a8[j] = sM[(qd * 8 + j) * 328 + d];
    f32x4 acc = {};
    acc = MFMA16(*(const bf16x8*)a8, batt, acc);
    if (lm < 8) {
      #pragma unroll
      for (int r = 0; r < 4; ++r)
        qn[(dtile * 16 + qd * 4 + r) * 8 + lm] = f2bf(acc[r]);
    }
  }
}

// =================== K3a: x = mbar @ wvf^T (m97-structure, gload_lds) =======
__global__ __launch_bounds__(512, 1)
void tgat_xgemm(const unsigned short* __restrict__ ws,
                const unsigned short* __restrict__ qkm, float* __restrict__ xacc)
{
  __shared__ alignas(16) unsigned short sA[2][128 * 128];  // 64 KB
  __shared__ alignas(16) unsigned short sB[2][80 * 128];   // 40 KB
  const int tid = threadIdx.x, wid = tid >> 6, lane = tid & 63;
  const int qd = lane >> 4, lm = lane & 15;
  const int xcd = blockIdx.x & 7, j = blockIdx.x >> 3;
  const int nb = j & 3, mb = xcd + 8 * (j >> 2);
  const int n0 = mb * 128, c0 = nb * 80;
  const unsigned short* wvf = ws + WS_WVF;

  const int rhi = lane >> 4, blo = lane & 15;

  #define STAGE(kc, buf) {                                                     \
    for (int ri = wid; ri < 52; ri += 8) {                                     \
      if (ri < 32) {                                                           \
        int r = ri * 4 + rhi;                                                  \
        int blk = blo ^ (r & 7);                                               \
        GLDS(qkm + (size_t)(n0 + r) * 2560 + (kc) * 128 + blk * 8,             \
             &sA[buf][ri * 512]);                                              \
      } else {                                                                 \
        int jb = ri - 32;                                                      \
        int r = jb * 4 + rhi;                                                  \
        int blk = blo ^ (r & 7);                                               \
        GLDS(wvf + (size_t)(c0 + r) * 2560 + (kc) * 128 + blk * 8,             \
             &sB[buf][jb * 512]);                                              \
      }                                                                        \
    } }

  f32x4 acc[5] = {};
  STAGE(0, 0);
  __syncthreads();

  for (int c = 0; c < 20; ++c) {
    if (c < 19) STAGE(c + 1, (c + 1) & 1);      // issue-early into other buffer
    const unsigned short* Ab = sA[c & 1];
    const unsigned short* Bb = sB[c & 1];
    const int s = lm & 7;
    #pragma unroll
    for (int kt = 0; kt < 4; ++kt) {
      const int blk = ((kt << 2) | qd) ^ s;
      bf16x8 a = *(const bf16x8*)&Ab[(wid * 16 + lm) * 128 + blk * 8];
      #pragma unroll
      for (int u = 0; u < 5; ++u) {
        bf16x8 b = *(const bf16x8*)&Bb[(u * 16 + lm) * 128 + blk * 8];
        acc[u] = MFMA16(a, b, acc[u]);
      }
    }
    __syncthreads();                             // drains staging, frees buffer
  }

  #pragma unroll
  for (int u = 0; u < 5; ++u)
    #pragma unroll
    for (int r = 0; r < 4; ++r)
      xacc[(size_t)(n0 + wid * 16 + qd * 4 + r) * 320 + c0 + u * 16 + lm] = acc[u][r];
  #undef STAGE
}

// =================== K3b: LN + out GEMM (512 blocks) ========================
__global__ __launch_bounds__(256, 4)
void tgat_post2(const float* __restrict__ nf, const unsigned short* __restrict__ ws,
                const float* __restrict__ xacc, float* __restrict__ out)
{
  __shared__ alignas(16) unsigned short sQb[16 * 136];
  __shared__ alignas(16) unsigned short sXb[16 * 328];
  const int tid = threadIdx.x, wid = tid >> 6, lane = tid & 63, qd = lane >> 4, lm = lane & 15;
  const int n0 = blockIdx.x * 16;
  const unsigned short* nwc = ws + WS_NWC;
  const float* f32r = (const float*)(ws + WS_F32);

  { // stage h_dst bf16
    int nn = tid >> 4, kk = (tid & 15) * 8;
    const float4* src = (const float4*)(nf + (size_t)(n0 + nn) * NODE_IN + kk);
    float4 f0 = src[0], f1 = src[1];
    float v8[8] = {f0.x, f0.y, f0.z, f0.w, f1.x, f1.y, f1.z, f1.w};
    *(bf16x8*)&sQb[nn * 136 + kk] = pack8(v8);
  }
  // LN: thread owns (row rr, cols cl+16u); reduce over the 16-lane row group
  const int rr = tid >> 4, cl = tid & 15;
  float v[20], s1 = 0.f, s2 = 0.f;
  #pragma unroll
  for (int u = 0; u < 20; ++u) {
    int c = u * 16 + cl;
    float x = xacc[(size_t)(n0 + rr) * 320 + c] + f32r[F_CC + c];
    if (c < 128) x += nf[(size_t)(n0 + rr) * NODE_IN + c];
    v[u] = x; s1 += x; s2 += x * x;
  }
  #pragma unroll
  for (int off = 8; off >= 1; off >>= 1) { s1 += __shfl_xor(s1, off); s2 += __shfl_xor(s2, off); }
  float mean = s1 * (1.f / D_MODEL);
  float var  = s2 * (1.f / D_MODEL) - mean * mean;
  float rstd = rsqrtf(var + 1e-5f);
  #pragma unroll
  for (int u = 0; u < 20; ++u) {
    int c = u * 16 + cl;
    sXb[rr * 328 + c] = f2bf((v[u] - mean) * rstd);
  }
  __syncthreads();

  // out GEMM: M=16, N=128, K=448; 4 waves x 2 o-tiles
  #pragma unroll
  for (int t = 0; t < 2; ++t) {
    int o = (wid * 2 + t) * 16 + lm;
    f32x4 acc = {};
    for (int kt = 0; kt < 14; ++kt) {
      bf16x8 a;
      if (kt < 4) a = *(const bf16x8*)&sQb[lm * 136 + kt * 32 + qd * 8];
      else        a = *(const bf16x8*)&sXb[lm * 328 + (kt - 4) * 32 + qd * 8];
      bf16x8 b = *(const bf16x8*)&nwc[(size_t)o * IN2 + kt * 32 + qd * 8];
      acc = MFMA16(a, b, acc);
    }
    float bz = f32r[F_B2 + o];
    #pragma unroll
    for (int r = 0; r < 4; ++r)
      out[(size_t)(n0 + qd * 4 + r) * HID + o] = fmaxf(acc[r] + bz, 0.f);
  }
}

extern "C" void kernel_launch(void* const* d_in, const int* in_sizes, int n_in,
                              void* d_out, int out_size, void* d_ws, size_t ws_size,
                              hipStream_t stream) {
  const float* nf   = (const float*)d_in[0];
  const float* ef   = (const float*)d_in[1];
  const float* dtp  = (const float*)d_in[2];
  const int*   nidx = (const int*)  d_in[3];
  const float* freq = (const float*)d_in[4];
  const float* ph   = (const float*)d_in[5];
  const float* wq   = (const float*)d_in[6];
  const float* wk   = (const float*)d_in[7];
  const float* wv   = (const float*)d_in[8];
  const float* fcw  = (const float*)d_in[9];
  const float* fcb  = (const float*)d_in[10];
  const float* lng  = (const float*)d_in[11];
  const float* lnb_ = (const float*)d_in[12];
  const float* nw   = (const float*)d_in[13];
  const float* nb   = (const float*)d_in[14];
  float* out = (float*)d_out;
  unsigned short* ws = (unsigned short*)d_ws;
  unsigned short* qkm = ws + WS_QKM;
  float* xacc = (float*)(ws + WS_X);

  prep_all<<<1266, 256, 0, stream>>>(nw, lng, fcb, ph, wq, lnb_, nb, wk, fcw, wv, ws);
  prep_c0k<<<640, 256, 0, stream>>>(wk, ws);
  tgat_qk   <<<2560, 256, 0, stream>>>(nf, ws, qkm);
  tgat_attn <<<8192, 256, 0, stream>>>(nf, ef, dtp, nidx, freq, ph, qkm);
  tgat_xgemm<<<256,  512, 0, stream>>>(ws, qkm, xacc);
  tgat_post2<<<512,  256, 0, stream>>>(nf, ws, xacc, out);
}

// Round 8
// 243.930 us; speedup vs baseline: 1.0719x; 1.0719x over previous
//
#include <hip/hip_runtime.h>
#include <math.h>

#define LNB      32
#define NODE_IN  128
#define EDGE_IN  64
#define TIME_D   128
#define D_MODEL  320
#define N_HEAD   8
#define D_K      64
#define NHD      512
#define HID      128
#define IN2      448
#define N_DSTN   8192

typedef __attribute__((ext_vector_type(8))) short bf16x8;
typedef __attribute__((ext_vector_type(4))) float f32x4;
#define MFMA16(a,b,c) __builtin_amdgcn_mfma_f32_16x16x32_bf16(a,b,c,0,0,0)

// ---- ws layout (elements of unsigned short) ----
#define WS_QKM   0            // 8192*2560 : qk (h-major) -> mbar (d*8+h layout), in place
#define WS_WQK   20971520     // 2560*128  : folded wk@wq   (row-major [h*320+d][k])
#define WS_WVF   21299200     // 320*2560  : folded fcw@wv  ([c][d*8+h])
#define WS_NWC   22118400     // 128*448   : [nw1 | nw2*lng]
#define WS_F32   22175744     // 3520 floats
#define WS_X     22182784     // 8192*320 f32 x buffer (plain stores, full-K blocks)
// total = 27,425,664 shorts = 54.9 MB

#define F_C0     0            // 512
#define F_C0K    512          // 2560
#define F_CC     3072         // 320 : fcb + q-const residual
#define F_B2     3392         // 128 : nb + nw2@lnb

// native RTNE f32->bf16 (v_cvt_pk_bf16_f32 on gfx950) — bit-identical to manual RTNE
__device__ __forceinline__ unsigned short f2bf(float f) {
  __bf16 h = (__bf16)f;
  return __builtin_bit_cast(unsigned short, h);
}
__device__ __forceinline__ bf16x8 pack8(const float* v) {
  unsigned short b8[8];
  #pragma unroll
  for (int j = 0; j < 8; ++j) b8[j] = f2bf(v[j]);
  return *(const bf16x8*)b8;
}

// async global->LDS, 16 B per lane; LDS dest = wave-uniform base + lane*16
#define GLDS(srcp, dstp) __builtin_amdgcn_global_load_lds(                     \
    (const __attribute__((address_space(1))) unsigned int*)(const void*)(srcp),\
    (__attribute__((address_space(3))) unsigned int*)(void*)(dstp), 16, 0, 0)

// =================== prep_all: 4 independent preps, one launch ==============
// blocks [0,226): prep1a  | [226,386): prep1b | [386,466): wqk | [466,1266): wvf
__global__ __launch_bounds__(256)
void prep_all(const float* __restrict__ nw, const float* __restrict__ lng,
              const float* __restrict__ fcb, const float* __restrict__ ph,
              const float* __restrict__ wq, const float* __restrict__ lnb_,
              const float* __restrict__ nb, const float* __restrict__ wk,
              const float* __restrict__ fcw, const float* __restrict__ wv,
              unsigned short* __restrict__ ws)
{
  __shared__ float smem[10240];          // 40 KB union
  const int b = blockIdx.x, tid = threadIdx.x;
  unsigned short* nwc = ws + WS_NWC;
  float* f32r = (float*)(ws + WS_F32);

  if (b < 226) {                         // ---- prep1a: elementwise folds ----
    int i = b * 256 + tid;
    if (i < 16384) {                     // nw1 cast
      int o = i >> 7, k = i & 127;
      nwc[o * IN2 + k] = f2bf(nw[(size_t)o * IN2 + k]);
    } else if (i < 57344) {              // nw2g = nw2 * lng
      int j = i - 16384, o = j / 320, c = j - o * 320;
      nwc[o * IN2 + 128 + c] = f2bf(nw[(size_t)o * IN2 + 128 + c] * lng[c]);
    } else if (i < 57664) {              // cc[c] = fcb + q-const
      int c = i - 57344;
      f32r[F_CC + c] = fcb[c] + (c >= 192 ? __cosf(ph[c - 192]) : 0.f);
    }
  } else if (b < 386) {                  // ---- prep1b: c0 + b2 ----
    int gw = ((b - 226) * 256 + tid) >> 6;
    int ln = tid & 63;
    if (gw < 512) {                      // c0[j] = cos(ph) . wq[j][192:]
      float s = __cosf(ph[ln])      * wq[(size_t)gw * D_MODEL + 192 + ln]
              + __cosf(ph[ln + 64]) * wq[(size_t)gw * D_MODEL + 256 + ln];
      #pragma unroll
      for (int off = 32; off >= 1; off >>= 1) s += __shfl_xor(s, off);
      if (ln == 0) f32r[F_C0 + gw] = s;
    } else {                             // b2[o] = nb + nw2 . lnb
      int o = gw - 512;
      float s = 0.f;
      #pragma unroll
      for (int k = 0; k < 5; ++k) {
        int c = ln + 64 * k;
        s += nw[(size_t)o * IN2 + 128 + c] * lnb_[c];
      }
      #pragma unroll
      for (int off = 32; off >= 1; off >>= 1) s += __shfl_xor(s, off);
      if (ln == 0) f32r[F_B2 + o] = nb[o] + s;
    }
  } else if (b < 466) {                  // ---- prep_wqk fold ----
    float* sQw = smem;                   // 64*128
    float* sKw = smem + 8192;            // 64*32
    int bw = b - 386;
    int h = bw / 10, d0 = (bw - h * 10) * 32;
    #pragma unroll 4
    for (int it = 0; it < 32; ++it) {
      int idx = it * 256 + tid;
      int r = idx >> 7, c = idx & 127;
      sQw[idx] = wq[(size_t)(h * 64 + r) * D_MODEL + c];
    }
    #pragma unroll
    for (int it = 0; it < 8; ++it) {
      int idx = it * 256 + tid;
      int r = idx >> 5, c = idx & 31;
      sKw[idx] = wk[(size_t)(h * 64 + r) * D_MODEL + d0 + c];
    }
    __syncthreads();
    int di = tid >> 3, k0 = (tid & 7) * 16;
    float acc[16] = {};
    for (int dk = 0; dk < 64; ++dk) {
      float w = sKw[dk * 32 + di];
      #pragma unroll
      for (int j = 0; j < 16; ++j) acc[j] += w * sQw[dk * 128 + k0 + j];
    }
    unsigned short* dst = ws + WS_WQK + (size_t)(h * 320 + d0 + di) * 128 + k0;
    #pragma unroll
    for (int j = 0; j < 16; ++j) dst[j] = f2bf(acc[j]);
  } else {                               // ---- prep_wvf fold ----
    float* sF = smem;                    // 32*64
    float* sW = smem + 2048;             // 64*32
    int bb = b - 466;
    int h = bb / 100, r2 = bb - h * 100;
    int ct = r2 / 10;
    int c0 = ct * 32, d0 = (r2 - ct * 10) * 32;
    #pragma unroll
    for (int it = 0; it < 8; ++it) {
      int idx = it * 256 + tid;
      int i = idx >> 6, jj = idx & 63;
      sF[idx] = fcw[(size_t)(c0 + i) * NHD + h * 64 + jj];
    }
    #pragma unroll
    for (int it = 0; it < 8; ++it) {
      int idx = it * 256 + tid;
      int jj = idx >> 5, i = idx & 31;
      sW[idx] = wv[(size_t)(h * 64 + jj) * D_MODEL + d0 + i];
    }
    __syncthreads();
    int ci = tid >> 3, dj0 = (tid & 7) * 4;
    float acc[4] = {};
    for (int jj = 0; jj < 64; ++jj) {
      float f = sF[ci * 64 + jj];
      #pragma unroll
      for (int k = 0; k < 4; ++k) acc[k] += f * sW[jj * 32 + dj0 + k];
    }
    unsigned short* wvf = ws + WS_WVF;
    #pragma unroll
    for (int k = 0; k < 4; ++k)
      wvf[(size_t)(c0 + ci) * 2560 + (size_t)(d0 + dj0 + k) * 8 + h] = f2bf(acc[k]);
  }
}

// =================== prep_c0k: one wave per hd ==============================
__global__ __launch_bounds__(256)
void prep_c0k(const float* __restrict__ wk, unsigned short* __restrict__ ws)
{
  float* f32r = (float*)(ws + WS_F32);
  int gw = (blockIdx.x * 256 + threadIdx.x) >> 6;   // 0..2559
  int ln = threadIdx.x & 63;
  int h = gw / 320, d = gw - h * 320;
  float s = f32r[F_C0 + h * 64 + ln] * wk[(size_t)(h * 64 + ln) * D_MODEL + d];
  #pragma unroll
  for (int off = 32; off >= 1; off >>= 1) s += __shfl_xor(s, off);
  if (ln == 0) f32r[F_C0K + gw] = s;
}

// =================== K1: qk = nf @ wqk^T + c0k  (h-major layout) ============
__global__ __launch_bounds__(256, 6)
void tgat_qk(const float* __restrict__ nf, const unsigned short* __restrict__ ws,
             unsigned short* __restrict__ qkm)
{
  __shared__ alignas(16) unsigned short sA[64 * 136];
  const int tid = threadIdx.x, wid = tid >> 6, lane = tid & 63, qd = lane >> 4, lm = lane & 15;
  const int mt_blk = blockIdx.x / 20, nt_blk = blockIdx.x - mt_blk * 20;
  const int n0 = mt_blk * 64, c0 = nt_blk * 128;
  const unsigned short* wqk = ws + WS_WQK;
  const float* f32r = (const float*)(ws + WS_F32);

  { // stage A: 64 x 128 bf16 (coalesced)
    int n = tid >> 2, k0 = (tid & 3) * 32;
    const float4* src = (const float4*)(nf + (size_t)(n0 + n) * NODE_IN + k0);
    #pragma unroll
    for (int q = 0; q < 4; ++q) {
      float4 f0 = src[2 * q], f1 = src[2 * q + 1];
      float v[8] = {f0.x, f0.y, f0.z, f0.w, f1.x, f1.y, f1.z, f1.w};
      *(bf16x8*)&sA[n * 136 + k0 + q * 8] = pack8(v);
    }
  }
  __syncthreads();

  f32x4 acc[2][4] = {};
  for (int kt = 0; kt < 4; ++kt) {
    bf16x8 a[4];
    #pragma unroll
    for (int mt = 0; mt < 4; ++mt)
      a[mt] = *(const bf16x8*)&sA[(mt * 16 + lm) * 136 + kt * 32 + qd * 8];
    #pragma unroll
    for (int t = 0; t < 2; ++t) {
      int cg = c0 + (2 * wid + t) * 16 + lm;
      bf16x8 b = *(const bf16x8*)&wqk[(size_t)cg * 128 + kt * 32 + qd * 8];
      #pragma unroll
      for (int mt = 0; mt < 4; ++mt) acc[t][mt] = MFMA16(a[mt], b, acc[t][mt]);
    }
  }
  #pragma unroll
  for (int t = 0; t < 2; ++t) {
    int cg = c0 + (2 * wid + t) * 16 + lm;
    float ck = f32r[F_C0K + cg];
    #pragma unroll
    for (int mt = 0; mt < 4; ++mt)
      #pragma unroll
      for (int r = 0; r < 4; ++r)
        qkm[(size_t)(n0 + mt * 16 + qd * 4 + r) * 2560 + cg] = f2bf(acc[t][mt][r] + ck);
  }
}

// =================== K2: attention (round-5 structure + sM col-swizzle) =====
// sM stores m[l][d] at column (d ^ ((l>>3)<<4)): for the transposed mbar
// reads (rows qd*8+j, fixed col) the XOR is lane-uniform (qd<<4), putting
// the 4 qd-groups on disjoint bank octets -> 2 lanes/bank (free) instead of
// 8-way. Writes stay contiguous and 16B-aligned (XOR touches bits 4-5 only).
__global__ __launch_bounds__(256, 7)
void tgat_attn(const float* __restrict__ nf, const float* __restrict__ ef,
               const float* __restrict__ dtp, const int* __restrict__ nidx,
               const float* __restrict__ freq, const float* __restrict__ ph,
               unsigned short* __restrict__ qkm)
{
  __shared__ alignas(16) unsigned short sM[LNB * 328];    // 21 KB (swizzled cols)
  __shared__ alignas(16) unsigned short sATT[16 * 40];    // 1.25 KB

  const int tid = threadIdx.x;
  const int wid = tid >> 6, lane = tid & 63, qd = lane >> 4, lm = lane & 15;
  const int n = blockIdx.x;
  unsigned short* qn = qkm + (size_t)n * 2560;

  // ---- m build: thread -> (l = g&31, 8 consecutive d); tables direct from L2
  #pragma unroll 1
  for (int it = 0; it < 5; ++it) {
    int g = it * 256 + tid;
    int l = g & 31, dg = g >> 5;
    int d0 = dg * 8;
    float v[8];
    if (dg < 16) {
      int ni = nidx[n * 16 + (l >> 1)];
      const float4* src = (const float4*)(nf + (size_t)ni * NODE_IN + d0);
      float4 f0 = src[0], f1 = src[1];
      v[0]=f0.x; v[1]=f0.y; v[2]=f0.z; v[3]=f0.w; v[4]=f1.x; v[5]=f1.y; v[6]=f1.z; v[7]=f1.w;
    } else if (dg < 24) {
      const float4* src = (const float4*)(ef + ((size_t)n * LNB + l) * EDGE_IN + (d0 - NODE_IN));
      float4 f0 = src[0], f1 = src[1];
      v[0]=f0.x; v[1]=f0.y; v[2]=f0.z; v[3]=f0.w; v[4]=f1.x; v[5]=f1.y; v[6]=f1.z; v[7]=f1.w;
    } else {
      int dd = d0 - 192;
      float dt = dtp[(size_t)n * LNB + l];
      const float4* fq = (const float4*)(freq + dd);
      const float4* pp = (const float4*)(ph + dd);
      float4 q0 = fq[0], q1 = fq[1], p0 = pp[0], p1 = pp[1];
      v[0] = __cosf(dt * q0.x + p0.x); v[1] = __cosf(dt * q0.y + p0.y);
      v[2] = __cosf(dt * q0.z + p0.z); v[3] = __cosf(dt * q0.w + p0.w);
      v[4] = __cosf(dt * q1.x + p1.x); v[5] = __cosf(dt * q1.y + p1.y);
      v[6] = __cosf(dt * q1.z + p1.z); v[7] = __cosf(dt * q1.w + p1.w);
    }
    *(bf16x8*)&sM[l * 328 + (d0 ^ ((l & 24) << 1))] = pack8(v);
  }

  // wave0: issue qk B-frag loads now — latency hides under the barrier wait
  bf16x8 qfrag[10];
  if (wid == 0) {
    #pragma unroll
    for (int kt = 0; kt < 10; ++kt) {
      qfrag[kt] = (bf16x8){0,0,0,0,0,0,0,0};
      if (lm < 8) qfrag[kt] = *(const bf16x8*)&qn[lm * 320 + kt * 32 + qd * 8];
    }
  }
  __syncthreads();                       // barrier 1: m ready

  // mbar tile ownership: wave0 -> 2 tiles, waves1-3 -> 6 each (20 total)
  const int tbeg = (wid == 0) ? 0 : 2 + (wid - 1) * 6;
  const int tcnt = (wid == 0) ? 2 : 6;
  bf16x8 afr[6];

  if (wid == 0) {
    // scores: D[l][h] = m @ qk^T / 8 (row-dependent col XOR)
    const int xa = (lm & 8) << 1;        // swz(lm), lm<16
    const int xb = 32 + xa;              // swz(16+lm)
    f32x4 acc0 = {}, acc1 = {};
    #pragma unroll
    for (int kt = 0; kt < 10; ++kt) {
      bf16x8 a0 = *(const bf16x8*)&sM[lm * 328 + ((kt * 32 + qd * 8) ^ xa)];
      bf16x8 a1 = *(const bf16x8*)&sM[(16 + lm) * 328 + ((kt * 32 + qd * 8) ^ xb)];
      acc0 = MFMA16(a0, qfrag[kt], acc0);
      acc1 = MFMA16(a1, qfrag[kt], acc1);
    }
    float s[8], e[8];
    #pragma unroll
    for (int r = 0; r < 4; ++r) { s[r] = acc0[r] * 0.125f; s[4 + r] = acc1[r] * 0.125f; }
    float mx = s[0];
    #pragma unroll
    for (int i = 1; i < 8; ++i) mx = fmaxf(mx, s[i]);
    mx = fmaxf(mx, __shfl_xor(mx, 16));
    mx = fmaxf(mx, __shfl_xor(mx, 32));
    float sum = 0.f;
    #pragma unroll
    for (int i = 0; i < 8; ++i) { e[i] = __expf(s[i] - mx); sum += e[i]; }
    sum += __shfl_xor(sum, 16);
    sum += __shfl_xor(sum, 32);
    float inv = 1.f / sum;
    #pragma unroll
    for (int i = 0; i < 8; ++i) {
      int l = (i < 4) ? (qd * 4 + i) : (16 + qd * 4 + (i - 4));
      sATT[lm * 40 + l] = f2bf(e[i] * inv);
    }
  } else {
    // waves 1-3: prefetch transposed-m A-frags for my 6 tiles (overlaps softmax)
    #pragma unroll
    for (int u = 0; u < 6; ++u) {
      int dc = ((tbeg + u) * 16 + lm) ^ (qd << 4);   // lane-uniform row XOR
      unsigned short a8[8];
      #pragma unroll
      for (int j = 0; j < 8; ++j) a8[j] = sM[(qd * 8 + j) * 328 + dc];
      afr[u] = *(const bf16x8*)a8;
    }
  }
  __syncthreads();                       // barrier 2: sATT ready

  if (wid == 0) {                        // wave0 fetches its 2 tiles now
    #pragma unroll
    for (int u = 0; u < 2; ++u) {
      int dc = (u * 16 + lm) ^ (qd << 4);
      unsigned short a8[8];
      #pragma unroll
      for (int j = 0; j < 8; ++j) a8[j] = sM[(qd * 8 + j) * 328 + dc];
      afr[u] = *(const bf16x8*)a8;
    }
  }
  bf16x8 batt = *(const bf16x8*)&sATT[lm * 40 + qd * 8];
  #pragma unroll
  for (int u = 0; u < 6; ++u) {
    if (u < tcnt) {                      // wave-uniform guard
      int dtile = tbeg + u;
      f32x4 acc = {};
      acc = MFMA16(afr[u], batt, acc);
      if (lm < 8) {
        #pragma unroll
        for (int r = 0; r < 4; ++r)
          qn[(dtile * 16 + qd * 4 + r) * 8 + lm] = f2bf(acc[r]);
      }
    }
  }
}

// =================== K3a: x = mbar @ wvf^T (m97-structure, gload_lds) =======
__global__ __launch_bounds__(512, 1)
void tgat_xgemm(const unsigned short* __restrict__ ws,
                const unsigned short* __restrict__ qkm, float* __restrict__ xacc)
{
  __shared__ alignas(16) unsigned short sA[2][128 * 128];  // 64 KB
  __shared__ alignas(16) unsigned short sB[2][80 * 128];   // 40 KB
  const int tid = threadIdx.x, wid = tid >> 6, lane = tid & 63;
  const int qd = lane >> 4, lm = lane & 15;
  const int xcd = blockIdx.x & 7, j = blockIdx.x >> 3;
  const int nb = j & 3, mb = xcd + 8 * (j >> 2);
  const int n0 = mb * 128, c0 = nb * 80;
  const unsigned short* wvf = ws + WS_WVF;

  const int rhi = lane >> 4, blo = lane & 15;

  #define STAGE(kc, buf) {                                                     \
    for (int ri = wid; ri < 52; ri += 8) {                                     \
      if (ri < 32) {                                                           \
        int r = ri * 4 + rhi;                                                  \
        int blk = blo ^ (r & 7);                                               \
        GLDS(qkm + (size_t)(n0 + r) * 2560 + (kc) * 128 + blk * 8,             \
             &sA[buf][ri * 512]);                                              \
      } else {                                                                 \
        int jb = ri - 32;                                                      \
        int r = jb * 4 + rhi;                                                  \
        int blk = blo ^ (r & 7);                                               \
        GLDS(wvf + (size_t)(c0 + r) * 2560 + (kc) * 128 + blk * 8,             \
             &sB[buf][jb * 512]);                                              \
      }                                                                        \
    } }

  f32x4 acc[5] = {};
  STAGE(0, 0);
  __syncthreads();

  for (int c = 0; c < 20; ++c) {
    if (c < 19) STAGE(c + 1, (c + 1) & 1);      // issue-early into other buffer
    const unsigned short* Ab = sA[c & 1];
    const unsigned short* Bb = sB[c & 1];
    const int s = lm & 7;
    #pragma unroll
    for (int kt = 0; kt < 4; ++kt) {
      const int blk = ((kt << 2) | qd) ^ s;
      bf16x8 a = *(const bf16x8*)&Ab[(wid * 16 + lm) * 128 + blk * 8];
      #pragma unroll
      for (int u = 0; u < 5; ++u) {
        bf16x8 b = *(const bf16x8*)&Bb[(u * 16 + lm) * 128 + blk * 8];
        acc[u] = MFMA16(a, b, acc[u]);
      }
    }
    __syncthreads();                             // drains staging, frees buffer
  }

  #pragma unroll
  for (int u = 0; u < 5; ++u)
    #pragma unroll
    for (int r = 0; r < 4; ++r)
      xacc[(size_t)(n0 + wid * 16 + qd * 4 + r) * 320 + c0 + u * 16 + lm] = acc[u][r];
  #undef STAGE
}

// =================== K3b: LN + out GEMM (512 blocks) ========================
__global__ __launch_bounds__(256, 4)
void tgat_post2(const float* __restrict__ nf, const unsigned short* __restrict__ ws,
                const float* __restrict__ xacc, float* __restrict__ out)
{
  __shared__ alignas(16) unsigned short sQb[16 * 136];
  __shared__ alignas(16) unsigned short sXb[16 * 328];
  const int tid = threadIdx.x, wid = tid >> 6, lane = tid & 63, qd = lane >> 4, lm = lane & 15;
  const int n0 = blockIdx.x * 16;
  const unsigned short* nwc = ws + WS_NWC;
  const float* f32r = (const float*)(ws + WS_F32);

  { // stage h_dst bf16
    int nn = tid >> 4, kk = (tid & 15) * 8;
    const float4* src = (const float4*)(nf + (size_t)(n0 + nn) * NODE_IN + kk);
    float4 f0 = src[0], f1 = src[1];
    float v8[8] = {f0.x, f0.y, f0.z, f0.w, f1.x, f1.y, f1.z, f1.w};
    *(bf16x8*)&sQb[nn * 136 + kk] = pack8(v8);
  }
  // LN: thread owns (row rr, cols cl+16u); reduce over the 16-lane row group
  const int rr = tid >> 4, cl = tid & 15;
  float v[20], s1 = 0.f, s2 = 0.f;
  #pragma unroll
  for (int u = 0; u < 20; ++u) {
    int c = u * 16 + cl;
    float x = xacc[(size_t)(n0 + rr) * 320 + c] + f32r[F_CC + c];
    if (c < 128) x += nf[(size_t)(n0 + rr) * NODE_IN + c];
    v[u] = x; s1 += x; s2 += x * x;
  }
  #pragma unroll
  for (int off = 8; off >= 1; off >>= 1) { s1 += __shfl_xor(s1, off); s2 += __shfl_xor(s2, off); }
  float mean = s1 * (1.f / D_MODEL);
  float var  = s2 * (1.f / D_MODEL) - mean * mean;
  float rstd = rsqrtf(var + 1e-5f);
  #pragma unroll
  for (int u = 0; u < 20; ++u) {
    int c = u * 16 + cl;
    sXb[rr * 328 + c] = f2bf((v[u] - mean) * rstd);
  }
  __syncthreads();

  // out GEMM: M=16, N=128, K=448; 4 waves x 2 o-tiles
  #pragma unroll
  for (int t = 0; t < 2; ++t) {
    int o = (wid * 2 + t) * 16 + lm;
    f32x4 acc = {};
    for (int kt = 0; kt < 14; ++kt) {
      bf16x8 a;
      if (kt < 4) a = *(const bf16x8*)&sQb[lm * 136 + kt * 32 + qd * 8];
      else        a = *(const bf16x8*)&sXb[lm * 328 + (kt - 4) * 32 + qd * 8];
      bf16x8 b = *(const bf16x8*)&nwc[(size_t)o * IN2 + kt * 32 + qd * 8];
      acc = MFMA16(a, b, acc);
    }
    float bz = f32r[F_B2 + o];
    #pragma unroll
    for (int r = 0; r < 4; ++r)
      out[(size_t)(n0 + qd * 4 + r) * HID + o] = fmaxf(acc[r] + bz, 0.f);
  }
}

extern "C" void kernel_launch(void* const* d_in, const int* in_sizes, int n_in,
                              void* d_out, int out_size, void* d_ws, size_t ws_size,
                              hipStream_t stream) {
  const float* nf   = (const float*)d_in[0];
  const float* ef   = (const float*)d_in[1];
  const float* dtp  = (const float*)d_in[2];
  const int*   nidx = (const int*)  d_in[3];
  const float* freq = (const float*)d_in[4];
  const float* ph   = (const float*)d_in[5];
  const float* wq   = (const float*)d_in[6];
  const float* wk   = (const float*)d_in[7];
  const float* wv   = (const float*)d_in[8];
  const float* fcw  = (const float*)d_in[9];
  const float* fcb  = (const float*)d_in[10];
  const float* lng  = (const float*)d_in[11];
  const float* lnb_ = (const float*)d_in[12];
  const float* nw   = (const float*)d_in[13];
  const float* nb   = (const float*)d_in[14];
  float* out = (float*)d_out;
  unsigned short* ws = (unsigned short*)d_ws;
  unsigned short* qkm = ws + WS_QKM;
  float* xacc = (float*)(ws + WS_X);

  prep_all<<<1266, 256, 0, stream>>>(nw, lng, fcb, ph, wq, lnb_, nb, wk, fcw, wv, ws);
  prep_c0k<<<640, 256, 0, stream>>>(wk, ws);
  tgat_qk   <<<2560, 256, 0, stream>>>(nf, ws, qkm);
  tgat_attn <<<8192, 256, 0, stream>>>(nf, ef, dtp, nidx, freq, ph, qkm);
  tgat_xgemm<<<256,  512, 0, stream>>>(ws, qkm, xacc);
  tgat_post2<<<512,  256, 0, stream>>>(nf, ws, xacc, out);
}

// Round 9
// 243.346 us; speedup vs baseline: 1.0745x; 1.0024x over previous
//
#include <hip/hip_runtime.h>
#include <math.h>

#define LNB      32
#define NODE_IN  128
#define EDGE_IN  64
#define TIME_D   128
#define D_MODEL  320
#define N_HEAD   8
#define D_K      64
#define NHD      512
#define HID      128
#define IN2      448
#define N_DSTN   8192

typedef __attribute__((ext_vector_type(8))) short bf16x8;
typedef __attribute__((ext_vector_type(4))) float f32x4;
#define MFMA16(a,b,c) __builtin_amdgcn_mfma_f32_16x16x32_bf16(a,b,c,0,0,0)

// ---- ws layout (elements of unsigned short) ----
#define WS_QKM   0            // 8192*2560 : qk (h-major) -> mbar (d*8+h layout), in place
#define WS_WQK   20971520     // 2560*128  : folded wk@wq   (row-major [h*320+d][k])
#define WS_WVF   21299200     // 320*2560  : folded fcw@wv  ([c][d*8+h])
#define WS_NWC   22118400     // 128*448   : [nw1 | nw2*lng]
#define WS_F32   22175744     // 3520 floats
#define WS_X     22182784     // 8192*320 f32 x buffer (plain stores, full-K blocks)
// total = 27,425,664 shorts = 54.9 MB

#define F_C0     0            // 512
#define F_C0K    512          // 2560
#define F_CC     3072         // 320 : fcb + q-const residual
#define F_B2     3392         // 128 : nb + nw2@lnb

// native RTNE f32->bf16 (v_cvt_pk_bf16_f32 on gfx950) — bit-identical to manual RTNE
__device__ __forceinline__ unsigned short f2bf(float f) {
  __bf16 h = (__bf16)f;
  return __builtin_bit_cast(unsigned short, h);
}
__device__ __forceinline__ bf16x8 pack8(const float* v) {
  unsigned short b8[8];
  #pragma unroll
  for (int j = 0; j < 8; ++j) b8[j] = f2bf(v[j]);
  return *(const bf16x8*)b8;
}

// async global->LDS, 16 B per lane; LDS dest = wave-uniform base + lane*16
#define GLDS(srcp, dstp) __builtin_amdgcn_global_load_lds(                     \
    (const __attribute__((address_space(1))) unsigned int*)(const void*)(srcp),\
    (__attribute__((address_space(3))) unsigned int*)(void*)(dstp), 16, 0, 0)

// =================== prep_all: 4 independent preps, one launch ==============
// blocks [0,226): prep1a  | [226,386): prep1b | [386,466): wqk | [466,1266): wvf
__global__ __launch_bounds__(256)
void prep_all(const float* __restrict__ nw, const float* __restrict__ lng,
              const float* __restrict__ fcb, const float* __restrict__ ph,
              const float* __restrict__ wq, const float* __restrict__ lnb_,
              const float* __restrict__ nb, const float* __restrict__ wk,
              const float* __restrict__ fcw, const float* __restrict__ wv,
              unsigned short* __restrict__ ws)
{
  __shared__ float smem[10240];          // 40 KB union
  const int b = blockIdx.x, tid = threadIdx.x;
  unsigned short* nwc = ws + WS_NWC;
  float* f32r = (float*)(ws + WS_F32);

  if (b < 226) {                         // ---- prep1a: elementwise folds ----
    int i = b * 256 + tid;
    if (i < 16384) {                     // nw1 cast
      int o = i >> 7, k = i & 127;
      nwc[o * IN2 + k] = f2bf(nw[(size_t)o * IN2 + k]);
    } else if (i < 57344) {              // nw2g = nw2 * lng
      int j = i - 16384, o = j / 320, c = j - o * 320;
      nwc[o * IN2 + 128 + c] = f2bf(nw[(size_t)o * IN2 + 128 + c] * lng[c]);
    } else if (i < 57664) {              // cc[c] = fcb + q-const
      int c = i - 57344;
      f32r[F_CC + c] = fcb[c] + (c >= 192 ? __cosf(ph[c - 192]) : 0.f);
    }
  } else if (b < 386) {                  // ---- prep1b: c0 + b2 ----
    int gw = ((b - 226) * 256 + tid) >> 6;
    int ln = tid & 63;
    if (gw < 512) {                      // c0[j] = cos(ph) . wq[j][192:]
      float s = __cosf(ph[ln])      * wq[(size_t)gw * D_MODEL + 192 + ln]
              + __cosf(ph[ln + 64]) * wq[(size_t)gw * D_MODEL + 256 + ln];
      #pragma unroll
      for (int off = 32; off >= 1; off >>= 1) s += __shfl_xor(s, off);
      if (ln == 0) f32r[F_C0 + gw] = s;
    } else {                             // b2[o] = nb + nw2 . lnb
      int o = gw - 512;
      float s = 0.f;
      #pragma unroll
      for (int k = 0; k < 5; ++k) {
        int c = ln + 64 * k;
        s += nw[(size_t)o * IN2 + 128 + c] * lnb_[c];
      }
      #pragma unroll
      for (int off = 32; off >= 1; off >>= 1) s += __shfl_xor(s, off);
      if (ln == 0) f32r[F_B2 + o] = nb[o] + s;
    }
  } else if (b < 466) {                  // ---- prep_wqk fold ----
    float* sQw = smem;                   // 64*128
    float* sKw = smem + 8192;            // 64*32
    int bw = b - 386;
    int h = bw / 10, d0 = (bw - h * 10) * 32;
    #pragma unroll 4
    for (int it = 0; it < 32; ++it) {
      int idx = it * 256 + tid;
      int r = idx >> 7, c = idx & 127;
      sQw[idx] = wq[(size_t)(h * 64 + r) * D_MODEL + c];
    }
    #pragma unroll
    for (int it = 0; it < 8; ++it) {
      int idx = it * 256 + tid;
      int r = idx >> 5, c = idx & 31;
      sKw[idx] = wk[(size_t)(h * 64 + r) * D_MODEL + d0 + c];
    }
    __syncthreads();
    int di = tid >> 3, k0 = (tid & 7) * 16;
    float acc[16] = {};
    for (int dk = 0; dk < 64; ++dk) {
      float w = sKw[dk * 32 + di];
      #pragma unroll
      for (int j = 0; j < 16; ++j) acc[j] += w * sQw[dk * 128 + k0 + j];
    }
    unsigned short* dst = ws + WS_WQK + (size_t)(h * 320 + d0 + di) * 128 + k0;
    #pragma unroll
    for (int j = 0; j < 16; ++j) dst[j] = f2bf(acc[j]);
  } else {                               // ---- prep_wvf fold ----
    float* sF = smem;                    // 32*64
    float* sW = smem + 2048;             // 64*32
    int bb = b - 466;
    int h = bb / 100, r2 = bb - h * 100;
    int ct = r2 / 10;
    int c0 = ct * 32, d0 = (r2 - ct * 10) * 32;
    #pragma unroll
    for (int it = 0; it < 8; ++it) {
      int idx = it * 256 + tid;
      int i = idx >> 6, jj = idx & 63;
      sF[idx] = fcw[(size_t)(c0 + i) * NHD + h * 64 + jj];
    }
    #pragma unroll
    for (int it = 0; it < 8; ++it) {
      int idx = it * 256 + tid;
      int jj = idx >> 5, i = idx & 31;
      sW[idx] = wv[(size_t)(h * 64 + jj) * D_MODEL + d0 + i];
    }
    __syncthreads();
    int ci = tid >> 3, dj0 = (tid & 7) * 4;
    float acc[4] = {};
    for (int jj = 0; jj < 64; ++jj) {
      float f = sF[ci * 64 + jj];
      #pragma unroll
      for (int k = 0; k < 4; ++k) acc[k] += f * sW[jj * 32 + dj0 + k];
    }
    unsigned short* wvf = ws + WS_WVF;
    #pragma unroll
    for (int k = 0; k < 4; ++k)
      wvf[(size_t)(c0 + ci) * 2560 + (size_t)(d0 + dj0 + k) * 8 + h] = f2bf(acc[k]);
  }
}

// =================== prep_c0k: one wave per hd ==============================
__global__ __launch_bounds__(256)
void prep_c0k(const float* __restrict__ wk, unsigned short* __restrict__ ws)
{
  float* f32r = (float*)(ws + WS_F32);
  int gw = (blockIdx.x * 256 + threadIdx.x) >> 6;   // 0..2559
  int ln = threadIdx.x & 63;
  int h = gw / 320, d = gw - h * 320;
  float s = f32r[F_C0 + h * 64 + ln] * wk[(size_t)(h * 64 + ln) * D_MODEL + d];
  #pragma unroll
  for (int off = 32; off >= 1; off >>= 1) s += __shfl_xor(s, off);
  if (ln == 0) f32r[F_C0K + gw] = s;
}

// =================== K1: qk = nf @ wqk^T + c0k  (h-major layout) ============
__global__ __launch_bounds__(256, 6)
void tgat_qk(const float* __restrict__ nf, const unsigned short* __restrict__ ws,
             unsigned short* __restrict__ qkm)
{
  __shared__ alignas(16) unsigned short sA[64 * 136];
  const int tid = threadIdx.x, wid = tid >> 6, lane = tid & 63, qd = lane >> 4, lm = lane & 15;
  const int mt_blk = blockIdx.x / 20, nt_blk = blockIdx.x - mt_blk * 20;
  const int n0 = mt_blk * 64, c0 = nt_blk * 128;
  const unsigned short* wqk = ws + WS_WQK;
  const float* f32r = (const float*)(ws + WS_F32);

  { // stage A: 64 x 128 bf16 (coalesced)
    int n = tid >> 2, k0 = (tid & 3) * 32;
    const float4* src = (const float4*)(nf + (size_t)(n0 + n) * NODE_IN + k0);
    #pragma unroll
    for (int q = 0; q < 4; ++q) {
      float4 f0 = src[2 * q], f1 = src[2 * q + 1];
      float v[8] = {f0.x, f0.y, f0.z, f0.w, f1.x, f1.y, f1.z, f1.w};
      *(bf16x8*)&sA[n * 136 + k0 + q * 8] = pack8(v);
    }
  }
  __syncthreads();

  f32x4 acc[2][4] = {};
  for (int kt = 0; kt < 4; ++kt) {
    bf16x8 a[4];
    #pragma unroll
    for (int mt = 0; mt < 4; ++mt)
      a[mt] = *(const bf16x8*)&sA[(mt * 16 + lm) * 136 + kt * 32 + qd * 8];
    #pragma unroll
    for (int t = 0; t < 2; ++t) {
      int cg = c0 + (2 * wid + t) * 16 + lm;
      bf16x8 b = *(const bf16x8*)&wqk[(size_t)cg * 128 + kt * 32 + qd * 8];
      #pragma unroll
      for (int mt = 0; mt < 4; ++mt) acc[t][mt] = MFMA16(a[mt], b, acc[t][mt]);
    }
  }
  #pragma unroll
  for (int t = 0; t < 2; ++t) {
    int cg = c0 + (2 * wid + t) * 16 + lm;
    float ck = f32r[F_C0K + cg];
    #pragma unroll
    for (int mt = 0; mt < 4; ++mt)
      #pragma unroll
      for (int r = 0; r < 4; ++r)
        qkm[(size_t)(n0 + mt * 16 + qd * 4 + r) * 2560 + cg] = f2bf(acc[t][mt][r] + ck);
  }
}

// =================== K2: attention (r8 + fully-unrolled m-build) ============
// m-build fully unrolled: all 10 global loads (2 nf iters, 1 ef iter) issue
// together -> one latency window instead of five; branches resolve at
// compile time (it0/1 nf, it2 ef, it3/4 te). sM col-swizzle as r8.
__global__ __launch_bounds__(256, 7)
void tgat_attn(const float* __restrict__ nf, const float* __restrict__ ef,
               const float* __restrict__ dtp, const int* __restrict__ nidx,
               const float* __restrict__ freq, const float* __restrict__ ph,
               unsigned short* __restrict__ qkm)
{
  __shared__ alignas(16) unsigned short sM[LNB * 328];    // 21 KB (swizzled cols)
  __shared__ alignas(16) unsigned short sATT[16 * 40];    // 1.25 KB

  const int tid = threadIdx.x;
  const int wid = tid >> 6, lane = tid & 63, qd = lane >> 4, lm = lane & 15;
  const int n = blockIdx.x;
  unsigned short* qn = qkm + (size_t)n * 2560;

  // ---- m build: thread -> (l = g&31, 8 consecutive d); FULLY UNROLLED ----
  #pragma unroll
  for (int it = 0; it < 5; ++it) {
    int g = it * 256 + tid;
    int l = g & 31, dg = g >> 5;
    int d0 = dg * 8;
    float v[8];
    if (dg < 16) {
      int ni = nidx[n * 16 + (l >> 1)];
      const float4* src = (const float4*)(nf + (size_t)ni * NODE_IN + d0);
      float4 f0 = src[0], f1 = src[1];
      v[0]=f0.x; v[1]=f0.y; v[2]=f0.z; v[3]=f0.w; v[4]=f1.x; v[5]=f1.y; v[6]=f1.z; v[7]=f1.w;
    } else if (dg < 24) {
      const float4* src = (const float4*)(ef + ((size_t)n * LNB + l) * EDGE_IN + (d0 - NODE_IN));
      float4 f0 = src[0], f1 = src[1];
      v[0]=f0.x; v[1]=f0.y; v[2]=f0.z; v[3]=f0.w; v[4]=f1.x; v[5]=f1.y; v[6]=f1.z; v[7]=f1.w;
    } else {
      int dd = d0 - 192;
      float dt = dtp[(size_t)n * LNB + l];
      const float4* fq = (const float4*)(freq + dd);
      const float4* pp = (const float4*)(ph + dd);
      float4 q0 = fq[0], q1 = fq[1], p0 = pp[0], p1 = pp[1];
      v[0] = __cosf(dt * q0.x + p0.x); v[1] = __cosf(dt * q0.y + p0.y);
      v[2] = __cosf(dt * q0.z + p0.z); v[3] = __cosf(dt * q0.w + p0.w);
      v[4] = __cosf(dt * q1.x + p1.x); v[5] = __cosf(dt * q1.y + p1.y);
      v[6] = __cosf(dt * q1.z + p1.z); v[7] = __cosf(dt * q1.w + p1.w);
    }
    *(bf16x8*)&sM[l * 328 + (d0 ^ ((l & 24) << 1))] = pack8(v);
  }

  // wave0: issue qk B-frag loads now — latency hides under the barrier wait
  bf16x8 qfrag[10];
  if (wid == 0) {
    #pragma unroll
    for (int kt = 0; kt < 10; ++kt) {
      qfrag[kt] = (bf16x8){0,0,0,0,0,0,0,0};
      if (lm < 8) qfrag[kt] = *(const bf16x8*)&qn[lm * 320 + kt * 32 + qd * 8];
    }
  }
  __syncthreads();                       // barrier 1: m ready

  // mbar tile ownership: wave0 -> 2 tiles, waves1-3 -> 6 each (20 total)
  const int tbeg = (wid == 0) ? 0 : 2 + (wid - 1) * 6;
  const int tcnt = (wid == 0) ? 2 : 6;
  bf16x8 afr[6];

  if (wid == 0) {
    // scores: D[l][h] = m @ qk^T / 8 (row-dependent col XOR)
    const int xa = (lm & 8) << 1;        // swz(lm), lm<16
    const int xb = 32 + xa;              // swz(16+lm)
    f32x4 acc0 = {}, acc1 = {};
    #pragma unroll
    for (int kt = 0; kt < 10; ++kt) {
      bf16x8 a0 = *(const bf16x8*)&sM[lm * 328 + ((kt * 32 + qd * 8) ^ xa)];
      bf16x8 a1 = *(const bf16x8*)&sM[(16 + lm) * 328 + ((kt * 32 + qd * 8) ^ xb)];
      acc0 = MFMA16(a0, qfrag[kt], acc0);
      acc1 = MFMA16(a1, qfrag[kt], acc1);
    }
    float s[8], e[8];
    #pragma unroll
    for (int r = 0; r < 4; ++r) { s[r] = acc0[r] * 0.125f; s[4 + r] = acc1[r] * 0.125f; }
    float mx = s[0];
    #pragma unroll
    for (int i = 1; i < 8; ++i) mx = fmaxf(mx, s[i]);
    mx = fmaxf(mx, __shfl_xor(mx, 16));
    mx = fmaxf(mx, __shfl_xor(mx, 32));
    float sum = 0.f;
    #pragma unroll
    for (int i = 0; i < 8; ++i) { e[i] = __expf(s[i] - mx); sum += e[i]; }
    sum += __shfl_xor(sum, 16);
    sum += __shfl_xor(sum, 32);
    float inv = 1.f / sum;
    #pragma unroll
    for (int i = 0; i < 8; ++i) {
      int l = (i < 4) ? (qd * 4 + i) : (16 + qd * 4 + (i - 4));
      sATT[lm * 40 + l] = f2bf(e[i] * inv);
    }
  } else {
    // waves 1-3: prefetch transposed-m A-frags for my 6 tiles (overlaps softmax)
    #pragma unroll
    for (int u = 0; u < 6; ++u) {
      int dc = ((tbeg + u) * 16 + lm) ^ (qd << 4);   // lane-uniform row XOR
      unsigned short a8[8];
      #pragma unroll
      for (int j = 0; j < 8; ++j) a8[j] = sM[(qd * 8 + j) * 328 + dc];
      afr[u] = *(const bf16x8*)a8;
    }
  }
  __syncthreads();                       // barrier 2: sATT ready

  if (wid == 0) {                        // wave0 fetches its 2 tiles now
    #pragma unroll
    for (int u = 0; u < 2; ++u) {
      int dc = (u * 16 + lm) ^ (qd << 4);
      unsigned short a8[8];
      #pragma unroll
      for (int j = 0; j < 8; ++j) a8[j] = sM[(qd * 8 + j) * 328 + dc];
      afr[u] = *(const bf16x8*)a8;
    }
  }
  bf16x8 batt = *(const bf16x8*)&sATT[lm * 40 + qd * 8];
  #pragma unroll
  for (int u = 0; u < 6; ++u) {
    if (u < tcnt) {                      // wave-uniform guard
      int dtile = tbeg + u;
      f32x4 acc = {};
      acc = MFMA16(afr[u], batt, acc);
      if (lm < 8) {
        #pragma unroll
        for (int r = 0; r < 4; ++r)
          qn[(dtile * 16 + qd * 4 + r) * 8 + lm] = f2bf(acc[r]);
      }
    }
  }
}

// =================== K3a: x = mbar @ wvf^T (m97-structure, gload_lds) =======
__global__ __launch_bounds__(512, 1)
void tgat_xgemm(const unsigned short* __restrict__ ws,
                const unsigned short* __restrict__ qkm, float* __restrict__ xacc)
{
  __shared__ alignas(16) unsigned short sA[2][128 * 128];  // 64 KB
  __shared__ alignas(16) unsigned short sB[2][80 * 128];   // 40 KB
  const int tid = threadIdx.x, wid = tid >> 6, lane = tid & 63;
  const int qd = lane >> 4, lm = lane & 15;
  const int xcd = blockIdx.x & 7, j = blockIdx.x >> 3;
  const int nb = j & 3, mb = xcd + 8 * (j >> 2);
  const int n0 = mb * 128, c0 = nb * 80;
  const unsigned short* wvf = ws + WS_WVF;

  const int rhi = lane >> 4, blo = lane & 15;

  #define STAGE(kc, buf) {                                                     \
    for (int ri = wid; ri < 52; ri += 8) {                                     \
      if (ri < 32) {                                                           \
        int r = ri * 4 + rhi;                                                  \
        int blk = blo ^ (r & 7);                                               \
        GLDS(qkm + (size_t)(n0 + r) * 2560 + (kc) * 128 + blk * 8,             \
             &sA[buf][ri * 512]);                                              \
      } else {                                                                 \
        int jb = ri - 32;                                                      \
        int r = jb * 4 + rhi;                                                  \
        int blk = blo ^ (r & 7);                                               \
        GLDS(wvf + (size_t)(c0 + r) * 2560 + (kc) * 128 + blk * 8,             \
             &sB[buf][jb * 512]);                                              \
      }                                                                        \
    } }

  f32x4 acc[5] = {};
  STAGE(0, 0);
  __syncthreads();

  for (int c = 0; c < 20; ++c) {
    if (c < 19) STAGE(c + 1, (c + 1) & 1);      // issue-early into other buffer
    const unsigned short* Ab = sA[c & 1];
    const unsigned short* Bb = sB[c & 1];
    const int s = lm & 7;
    #pragma unroll
    for (int kt = 0; kt < 4; ++kt) {
      const int blk = ((kt << 2) | qd) ^ s;
      bf16x8 a = *(const bf16x8*)&Ab[(wid * 16 + lm) * 128 + blk * 8];
      #pragma unroll
      for (int u = 0; u < 5; ++u) {
        bf16x8 b = *(const bf16x8*)&Bb[(u * 16 + lm) * 128 + blk * 8];
        acc[u] = MFMA16(a, b, acc[u]);
      }
    }
    __syncthreads();                             // drains staging, frees buffer
  }

  #pragma unroll
  for (int u = 0; u < 5; ++u)
    #pragma unroll
    for (int r = 0; r < 4; ++r)
      xacc[(size_t)(n0 + wid * 16 + qd * 4 + r) * 320 + c0 + u * 16 + lm] = acc[u][r];
  #undef STAGE
}

// =================== K3b: LN + out GEMM (512 blocks) ========================
__global__ __launch_bounds__(256, 4)
void tgat_post2(const float* __restrict__ nf, const unsigned short* __restrict__ ws,
                const float* __restrict__ xacc, float* __restrict__ out)
{
  __shared__ alignas(16) unsigned short sQb[16 * 136];
  __shared__ alignas(16) unsigned short sXb[16 * 328];
  const int tid = threadIdx.x, wid = tid >> 6, lane = tid & 63, qd = lane >> 4, lm = lane & 15;
  const int n0 = blockIdx.x * 16;
  const unsigned short* nwc = ws + WS_NWC;
  const float* f32r = (const float*)(ws + WS_F32);

  { // stage h_dst bf16
    int nn = tid >> 4, kk = (tid & 15) * 8;
    const float4* src = (const float4*)(nf + (size_t)(n0 + nn) * NODE_IN + kk);
    float4 f0 = src[0], f1 = src[1];
    float v8[8] = {f0.x, f0.y, f0.z, f0.w, f1.x, f1.y, f1.z, f1.w};
    *(bf16x8*)&sQb[nn * 136 + kk] = pack8(v8);
  }
  // LN: thread owns (row rr, cols cl+16u); reduce over the 16-lane row group
  const int rr = tid >> 4, cl = tid & 15;
  float v[20], s1 = 0.f, s2 = 0.f;
  #pragma unroll
  for (int u = 0; u < 20; ++u) {
    int c = u * 16 + cl;
    float x = xacc[(size_t)(n0 + rr) * 320 + c] + f32r[F_CC + c];
    if (c < 128) x += nf[(size_t)(n0 + rr) * NODE_IN + c];
    v[u] = x; s1 += x; s2 += x * x;
  }
  #pragma unroll
  for (int off = 8; off >= 1; off >>= 1) { s1 += __shfl_xor(s1, off); s2 += __shfl_xor(s2, off); }
  float mean = s1 * (1.f / D_MODEL);
  float var  = s2 * (1.f / D_MODEL) - mean * mean;
  float rstd = rsqrtf(var + 1e-5f);
  #pragma unroll
  for (int u = 0; u < 20; ++u) {
    int c = u * 16 + cl;
    sXb[rr * 328 + c] = f2bf((v[u] - mean) * rstd);
  }
  __syncthreads();

  // out GEMM: M=16, N=128, K=448; 4 waves x 2 o-tiles
  #pragma unroll
  for (int t = 0; t < 2; ++t) {
    int o = (wid * 2 + t) * 16 + lm;
    f32x4 acc = {};
    for (int kt = 0; kt < 14; ++kt) {
      bf16x8 a;
      if (kt < 4) a = *(const bf16x8*)&sQb[lm * 136 + kt * 32 + qd * 8];
      else        a = *(const bf16x8*)&sXb[lm * 328 + (kt - 4) * 32 + qd * 8];
      bf16x8 b = *(const bf16x8*)&nwc[(size_t)o * IN2 + kt * 32 + qd * 8];
      acc = MFMA16(a, b, acc);
    }
    float bz = f32r[F_B2 + o];
    #pragma unroll
    for (int r = 0; r < 4; ++r)
      out[(size_t)(n0 + qd * 4 + r) * HID + o] = fmaxf(acc[r] + bz, 0.f);
  }
}

extern "C" void kernel_launch(void* const* d_in, const int* in_sizes, int n_in,
                              void* d_out, int out_size, void* d_ws, size_t ws_size,
                              hipStream_t stream) {
  const float* nf   = (const float*)d_in[0];
  const float* ef   = (const float*)d_in[1];
  const float* dtp  = (const float*)d_in[2];
  const int*   nidx = (const int*)  d_in[3];
  const float* freq = (const float*)d_in[4];
  const float* ph   = (const float*)d_in[5];
  const float* wq   = (const float*)d_in[6];
  const float* wk   = (const float*)d_in[7];
  const float* wv   = (const float*)d_in[8];
  const float* fcw  = (const float*)d_in[9];
  const float* fcb  = (const float*)d_in[10];
  const float* lng  = (const float*)d_in[11];
  const float* lnb_ = (const float*)d_in[12];
  const float* nw   = (const float*)d_in[13];
  const float* nb   = (const float*)d_in[14];
  float* out = (float*)d_out;
  unsigned short* ws = (unsigned short*)d_ws;
  unsigned short* qkm = ws + WS_QKM;
  float* xacc = (float*)(ws + WS_X);

  prep_all<<<1266, 256, 0, stream>>>(nw, lng, fcb, ph, wq, lnb_, nb, wk, fcw, wv, ws);
  prep_c0k<<<640, 256, 0, stream>>>(wk, ws);
  tgat_qk   <<<2560, 256, 0, stream>>>(nf, ws, qkm);
  tgat_attn <<<8192, 256, 0, stream>>>(nf, ef, dtp, nidx, freq, ph, qkm);
  tgat_xgemm<<<256,  512, 0, stream>>>(ws, qkm, xacc);
  tgat_post2<<<512,  256, 0, stream>>>(nf, ws, xacc, out);
}

// Round 10
// 242.790 us; speedup vs baseline: 1.0770x; 1.0023x over previous
//
#include <hip/hip_runtime.h>
#include <math.h>

#define LNB      32
#define NODE_IN  128
#define EDGE_IN  64
#define TIME_D   128
#define D_MODEL  320
#define N_HEAD   8
#define D_K      64
#define NHD      512
#define HID      128
#define IN2      448
#define N_DSTN   8192

typedef __attribute__((ext_vector_type(8))) short bf16x8;
typedef __attribute__((ext_vector_type(4))) float f32x4;
#define MFMA16(a,b,c) __builtin_amdgcn_mfma_f32_16x16x32_bf16(a,b,c,0,0,0)

// ---- ws layout (elements of unsigned short) ----
#define WS_QKM   0            // 8192*2560 : qk (h-major) -> mbar (d*8+h layout), in place
#define WS_WQK   20971520     // 2560*128  : folded wk@wq   (row-major [h*320+d][k])
#define WS_WVF   21299200     // 320*2560  : folded fcw@wv  ([c][d*8+h])
#define WS_NWC   22118400     // 128*448   : [nw1 | nw2*lng]
#define WS_F32   22175744     // 3520 floats
#define WS_X     22182784     // 8192*320 f32 x buffer (plain stores, full-K blocks)
// total = 27,425,664 shorts = 54.9 MB

#define F_C0     0            // 512
#define F_C0K    512          // 2560
#define F_CC     3072         // 320 : fcb + q-const residual
#define F_B2     3392         // 128 : nb + nw2@lnb

// native RTNE f32->bf16 (v_cvt_pk_bf16_f32 on gfx950) — bit-identical to manual RTNE
__device__ __forceinline__ unsigned short f2bf(float f) {
  __bf16 h = (__bf16)f;
  return __builtin_bit_cast(unsigned short, h);
}
__device__ __forceinline__ bf16x8 pack8(const float* v) {
  unsigned short b8[8];
  #pragma unroll
  for (int j = 0; j < 8; ++j) b8[j] = f2bf(v[j]);
  return *(const bf16x8*)b8;
}

// async global->LDS, 16 B per lane; LDS dest = wave-uniform base + lane*16
#define GLDS(srcp, dstp) __builtin_amdgcn_global_load_lds(                     \
    (const __attribute__((address_space(1))) unsigned int*)(const void*)(srcp),\
    (__attribute__((address_space(3))) unsigned int*)(void*)(dstp), 16, 0, 0)

// =================== prep_all: 4 independent preps, one launch ==============
// blocks [0,226): prep1a  | [226,386): prep1b | [386,466): wqk | [466,1266): wvf
__global__ __launch_bounds__(256)
void prep_all(const float* __restrict__ nw, const float* __restrict__ lng,
              const float* __restrict__ fcb, const float* __restrict__ ph,
              const float* __restrict__ wq, const float* __restrict__ lnb_,
              const float* __restrict__ nb, const float* __restrict__ wk,
              const float* __restrict__ fcw, const float* __restrict__ wv,
              unsigned short* __restrict__ ws)
{
  __shared__ float smem[10240];          // 40 KB union
  const int b = blockIdx.x, tid = threadIdx.x;
  unsigned short* nwc = ws + WS_NWC;
  float* f32r = (float*)(ws + WS_F32);

  if (b < 226) {                         // ---- prep1a: elementwise folds ----
    int i = b * 256 + tid;
    if (i < 16384) {                     // nw1 cast
      int o = i >> 7, k = i & 127;
      nwc[o * IN2 + k] = f2bf(nw[(size_t)o * IN2 + k]);
    } else if (i < 57344) {              // nw2g = nw2 * lng
      int j = i - 16384, o = j / 320, c = j - o * 320;
      nwc[o * IN2 + 128 + c] = f2bf(nw[(size_t)o * IN2 + 128 + c] * lng[c]);
    } else if (i < 57664) {              // cc[c] = fcb + q-const
      int c = i - 57344;
      f32r[F_CC + c] = fcb[c] + (c >= 192 ? __cosf(ph[c - 192]) : 0.f);
    }
  } else if (b < 386) {                  // ---- prep1b: c0 + b2 ----
    int gw = ((b - 226) * 256 + tid) >> 6;
    int ln = tid & 63;
    if (gw < 512) {                      // c0[j] = cos(ph) . wq[j][192:]
      float s = __cosf(ph[ln])      * wq[(size_t)gw * D_MODEL + 192 + ln]
              + __cosf(ph[ln + 64]) * wq[(size_t)gw * D_MODEL + 256 + ln];
      #pragma unroll
      for (int off = 32; off >= 1; off >>= 1) s += __shfl_xor(s, off);
      if (ln == 0) f32r[F_C0 + gw] = s;
    } else {                             // b2[o] = nb + nw2 . lnb
      int o = gw - 512;
      float s = 0.f;
      #pragma unroll
      for (int k = 0; k < 5; ++k) {
        int c = ln + 64 * k;
        s += nw[(size_t)o * IN2 + 128 + c] * lnb_[c];
      }
      #pragma unroll
      for (int off = 32; off >= 1; off >>= 1) s += __shfl_xor(s, off);
      if (ln == 0) f32r[F_B2 + o] = nb[o] + s;
    }
  } else if (b < 466) {                  // ---- prep_wqk fold ----
    float* sQw = smem;                   // 64*128
    float* sKw = smem + 8192;            // 64*32
    int bw = b - 386;
    int h = bw / 10, d0 = (bw - h * 10) * 32;
    #pragma unroll 4
    for (int it = 0; it < 32; ++it) {
      int idx = it * 256 + tid;
      int r = idx >> 7, c = idx & 127;
      sQw[idx] = wq[(size_t)(h * 64 + r) * D_MODEL + c];
    }
    #pragma unroll
    for (int it = 0; it < 8; ++it) {
      int idx = it * 256 + tid;
      int r = idx >> 5, c = idx & 31;
      sKw[idx] = wk[(size_t)(h * 64 + r) * D_MODEL + d0 + c];
    }
    __syncthreads();
    int di = tid >> 3, k0 = (tid & 7) * 16;
    float acc[16] = {};
    for (int dk = 0; dk < 64; ++dk) {
      float w = sKw[dk * 32 + di];
      #pragma unroll
      for (int j = 0; j < 16; ++j) acc[j] += w * sQw[dk * 128 + k0 + j];
    }
    unsigned short* dst = ws + WS_WQK + (size_t)(h * 320 + d0 + di) * 128 + k0;
    #pragma unroll
    for (int j = 0; j < 16; ++j) dst[j] = f2bf(acc[j]);
  } else {                               // ---- prep_wvf fold ----
    float* sF = smem;                    // 32*64
    float* sW = smem + 2048;             // 64*32
    int bb = b - 466;
    int h = bb / 100, r2 = bb - h * 100;
    int ct = r2 / 10;
    int c0 = ct * 32, d0 = (r2 - ct * 10) * 32;
    #pragma unroll
    for (int it = 0; it < 8; ++it) {
      int idx = it * 256 + tid;
      int i = idx >> 6, jj = idx & 63;
      sF[idx] = fcw[(size_t)(c0 + i) * NHD + h * 64 + jj];
    }
    #pragma unroll
    for (int it = 0; it < 8; ++it) {
      int idx = it * 256 + tid;
      int jj = idx >> 5, i = idx & 31;
      sW[idx] = wv[(size_t)(h * 64 + jj) * D_MODEL + d0 + i];
    }
    __syncthreads();
    int ci = tid >> 3, dj0 = (tid & 7) * 4;
    float acc[4] = {};
    for (int jj = 0; jj < 64; ++jj) {
      float f = sF[ci * 64 + jj];
      #pragma unroll
      for (int k = 0; k < 4; ++k) acc[k] += f * sW[jj * 32 + dj0 + k];
    }
    unsigned short* wvf = ws + WS_WVF;
    #pragma unroll
    for (int k = 0; k < 4; ++k)
      wvf[(size_t)(c0 + ci) * 2560 + (size_t)(d0 + dj0 + k) * 8 + h] = f2bf(acc[k]);
  }
}

// =================== prep_c0k: one wave per hd ==============================
__global__ __launch_bounds__(256)
void prep_c0k(const float* __restrict__ wk, unsigned short* __restrict__ ws)
{
  float* f32r = (float*)(ws + WS_F32);
  int gw = (blockIdx.x * 256 + threadIdx.x) >> 6;   // 0..2559
  int ln = threadIdx.x & 63;
  int h = gw / 320, d = gw - h * 320;
  float s = f32r[F_C0 + h * 64 + ln] * wk[(size_t)(h * 64 + ln) * D_MODEL + d];
  #pragma unroll
  for (int off = 32; off >= 1; off >>= 1) s += __shfl_xor(s, off);
  if (ln == 0) f32r[F_C0K + gw] = s;
}

// =================== K1: qk = nf @ wqk^T + c0k (LDS-B, coalesced epilogue) ==
// B-slice (128 rows x 256B, contiguous) staged via global_load_lds with
// source XOR pre-swizzle (rule #21): read blk = (kt*4+qd) ^ (row&7) -> 2
// lanes/bank (free). All MFMA operands from LDS. Epilogue transposes acc
// through LDS (overlay on sB after consumption) -> 64B/thread coalesced
// row-major stores instead of 64 scalar 5KB-strided u16 stores.
__global__ __launch_bounds__(256, 3)
void tgat_qk(const float* __restrict__ nf, const unsigned short* __restrict__ ws,
             unsigned short* __restrict__ qkm)
{
  __shared__ alignas(16) unsigned short sA[64 * 136];    // 17.4 KB
  __shared__ alignas(16) unsigned short sB[128 * 128];   // 32 KB; reused as out
  const int tid = threadIdx.x, wid = tid >> 6, lane = tid & 63, qd = lane >> 4, lm = lane & 15;
  const int mt_blk = blockIdx.x / 20, nt_blk = blockIdx.x - mt_blk * 20;
  const int n0 = mt_blk * 64, c0 = nt_blk * 128;
  const unsigned short* wqk = ws + WS_WQK;
  const float* f32r = (const float*)(ws + WS_F32);

  { // issue B staging (async vmcnt stream): 32 rounds of 1 KB (4 rows each)
    int r4 = lane >> 4, blk = lane & 15;
    for (int ri = wid; ri < 32; ri += 4) {
      int r = ri * 4 + r4;
      int sblk = blk ^ (r & 7);          // inverse-swizzled source
      GLDS(wqk + (size_t)(c0 + r) * 128 + sblk * 8, &sB[ri * 512]);
    }
  }
  { // stage A: 64 x 128 bf16 (pack from f32, coalesced)
    int n = tid >> 2, k0 = (tid & 3) * 32;
    const float4* src = (const float4*)(nf + (size_t)(n0 + n) * NODE_IN + k0);
    #pragma unroll
    for (int q = 0; q < 4; ++q) {
      float4 f0 = src[2 * q], f1 = src[2 * q + 1];
      float v[8] = {f0.x, f0.y, f0.z, f0.w, f1.x, f1.y, f1.z, f1.w};
      *(bf16x8*)&sA[n * 136 + k0 + q * 8] = pack8(v);
    }
  }
  __syncthreads();                       // drains vmcnt+lgkm: A and B ready

  f32x4 acc[2][4] = {};
  #pragma unroll
  for (int kt = 0; kt < 4; ++kt) {
    bf16x8 a[4];
    #pragma unroll
    for (int mt = 0; mt < 4; ++mt)
      a[mt] = *(const bf16x8*)&sA[(mt * 16 + lm) * 136 + kt * 32 + qd * 8];
    #pragma unroll
    for (int t = 0; t < 2; ++t) {
      int row = (2 * wid + t) * 16 + lm;               // local cg row
      int blk = (kt * 4 + qd) ^ (row & 7);             // swizzled read
      bf16x8 b = *(const bf16x8*)&sB[row * 128 + blk * 8];
      #pragma unroll
      for (int mt = 0; mt < 4; ++mt) acc[t][mt] = MFMA16(a[mt], b, acc[t][mt]);
    }
  }
  __syncthreads();                       // B fully consumed; overlay sOut on sB

  unsigned short* sOut = sB;             // 64 x 136 bf16 (8.7 K shorts <= 16 K)
  #pragma unroll
  for (int t = 0; t < 2; ++t) {
    int cl = (2 * wid + t) * 16 + lm;
    float ck = f32r[F_C0K + c0 + cl];
    #pragma unroll
    for (int mt = 0; mt < 4; ++mt)
      #pragma unroll
      for (int r = 0; r < 4; ++r)
        sOut[(mt * 16 + qd * 4 + r) * 136 + cl] = f2bf(acc[t][mt][r] + ck);
  }
  __syncthreads();

  { // coalesced store: thread -> row tid>>2, 32 cols at (tid&3)*32 (64 B)
    int rr = tid >> 2, cg = (tid & 3) * 32;
    unsigned short* dst = qkm + (size_t)(n0 + rr) * 2560 + c0 + cg;
    const unsigned short* srcp = &sOut[rr * 136 + cg];
    *(bf16x8*)(dst)      = *(const bf16x8*)(srcp);
    *(bf16x8*)(dst + 8)  = *(const bf16x8*)(srcp + 8);
    *(bf16x8*)(dst + 16) = *(const bf16x8*)(srcp + 16);
    *(bf16x8*)(dst + 24) = *(const bf16x8*)(srcp + 24);
  }
}

// =================== K2: attention (r9: swizzled sM, unrolled m-build) ======
__global__ __launch_bounds__(256, 7)
void tgat_attn(const float* __restrict__ nf, const float* __restrict__ ef,
               const float* __restrict__ dtp, const int* __restrict__ nidx,
               const float* __restrict__ freq, const float* __restrict__ ph,
               unsigned short* __restrict__ qkm)
{
  __shared__ alignas(16) unsigned short sM[LNB * 328];    // 21 KB (swizzled cols)
  __shared__ alignas(16) unsigned short sATT[16 * 40];    // 1.25 KB

  const int tid = threadIdx.x;
  const int wid = tid >> 6, lane = tid & 63, qd = lane >> 4, lm = lane & 15;
  const int n = blockIdx.x;
  unsigned short* qn = qkm + (size_t)n * 2560;

  // ---- m build: thread -> (l = g&31, 8 consecutive d); FULLY UNROLLED ----
  #pragma unroll
  for (int it = 0; it < 5; ++it) {
    int g = it * 256 + tid;
    int l = g & 31, dg = g >> 5;
    int d0 = dg * 8;
    float v[8];
    if (dg < 16) {
      int ni = nidx[n * 16 + (l >> 1)];
      const float4* src = (const float4*)(nf + (size_t)ni * NODE_IN + d0);
      float4 f0 = src[0], f1 = src[1];
      v[0]=f0.x; v[1]=f0.y; v[2]=f0.z; v[3]=f0.w; v[4]=f1.x; v[5]=f1.y; v[6]=f1.z; v[7]=f1.w;
    } else if (dg < 24) {
      const float4* src = (const float4*)(ef + ((size_t)n * LNB + l) * EDGE_IN + (d0 - NODE_IN));
      float4 f0 = src[0], f1 = src[1];
      v[0]=f0.x; v[1]=f0.y; v[2]=f0.z; v[3]=f0.w; v[4]=f1.x; v[5]=f1.y; v[6]=f1.z; v[7]=f1.w;
    } else {
      int dd = d0 - 192;
      float dt = dtp[(size_t)n * LNB + l];
      const float4* fq = (const float4*)(freq + dd);
      const float4* pp = (const float4*)(ph + dd);
      float4 q0 = fq[0], q1 = fq[1], p0 = pp[0], p1 = pp[1];
      v[0] = __cosf(dt * q0.x + p0.x); v[1] = __cosf(dt * q0.y + p0.y);
      v[2] = __cosf(dt * q0.z + p0.z); v[3] = __cosf(dt * q0.w + p0.w);
      v[4] = __cosf(dt * q1.x + p1.x); v[5] = __cosf(dt * q1.y + p1.y);
      v[6] = __cosf(dt * q1.z + p1.z); v[7] = __cosf(dt * q1.w + p1.w);
    }
    *(bf16x8*)&sM[l * 328 + (d0 ^ ((l & 24) << 1))] = pack8(v);
  }

  // wave0: issue qk B-frag loads now — latency hides under the barrier wait
  bf16x8 qfrag[10];
  if (wid == 0) {
    #pragma unroll
    for (int kt = 0; kt < 10; ++kt) {
      qfrag[kt] = (bf16x8){0,0,0,0,0,0,0,0};
      if (lm < 8) qfrag[kt] = *(const bf16x8*)&qn[lm * 320 + kt * 32 + qd * 8];
    }
  }
  __syncthreads();                       // barrier 1: m ready

  // mbar tile ownership: wave0 -> 2 tiles, waves1-3 -> 6 each (20 total)
  const int tbeg = (wid == 0) ? 0 : 2 + (wid - 1) * 6;
  const int tcnt = (wid == 0) ? 2 : 6;
  bf16x8 afr[6];

  if (wid == 0) {
    // scores: D[l][h] = m @ qk^T / 8 (row-dependent col XOR)
    const int xa = (lm & 8) << 1;        // swz(lm), lm<16
    const int xb = 32 + xa;              // swz(16+lm)
    f32x4 acc0 = {}, acc1 = {};
    #pragma unroll
    for (int kt = 0; kt < 10; ++kt) {
      bf16x8 a0 = *(const bf16x8*)&sM[lm * 328 + ((kt * 32 + qd * 8) ^ xa)];
      bf16x8 a1 = *(const bf16x8*)&sM[(16 + lm) * 328 + ((kt * 32 + qd * 8) ^ xb)];
      acc0 = MFMA16(a0, qfrag[kt], acc0);
      acc1 = MFMA16(a1, qfrag[kt], acc1);
    }
    float s[8], e[8];
    #pragma unroll
    for (int r = 0; r < 4; ++r) { s[r] = acc0[r] * 0.125f; s[4 + r] = acc1[r] * 0.125f; }
    float mx = s[0];
    #pragma unroll
    for (int i = 1; i < 8; ++i) mx = fmaxf(mx, s[i]);
    mx = fmaxf(mx, __shfl_xor(mx, 16));
    mx = fmaxf(mx, __shfl_xor(mx, 32));
    float sum = 0.f;
    #pragma unroll
    for (int i = 0; i < 8; ++i) { e[i] = __expf(s[i] - mx); sum += e[i]; }
    sum += __shfl_xor(sum, 16);
    sum += __shfl_xor(sum, 32);
    float inv = 1.f / sum;
    #pragma unroll
    for (int i = 0; i < 8; ++i) {
      int l = (i < 4) ? (qd * 4 + i) : (16 + qd * 4 + (i - 4));
      sATT[lm * 40 + l] = f2bf(e[i] * inv);
    }
  } else {
    // waves 1-3: prefetch transposed-m A-frags for my 6 tiles (overlaps softmax)
    #pragma unroll
    for (int u = 0; u < 6; ++u) {
      int dc = ((tbeg + u) * 16 + lm) ^ (qd << 4);   // lane-uniform row XOR
      unsigned short a8[8];
      #pragma unroll
      for (int j = 0; j < 8; ++j) a8[j] = sM[(qd * 8 + j) * 328 + dc];
      afr[u] = *(const bf16x8*)a8;
    }
  }
  __syncthreads();                       // barrier 2: sATT ready

  if (wid == 0) {                        // wave0 fetches its 2 tiles now
    #pragma unroll
    for (int u = 0; u < 2; ++u) {
      int dc = (u * 16 + lm) ^ (qd << 4);
      unsigned short a8[8];
      #pragma unroll
      for (int j = 0; j < 8; ++j) a8[j] = sM[(qd * 8 + j) * 328 + dc];
      afr[u] = *(const bf16x8*)a8;
    }
  }
  bf16x8 batt = *(const bf16x8*)&sATT[lm * 40 + qd * 8];
  #pragma unroll
  for (int u = 0; u < 6; ++u) {
    if (u < tcnt) {                      // wave-uniform guard
      int dtile = tbeg + u;
      f32x4 acc = {};
      acc = MFMA16(afr[u], batt, acc);
      if (lm < 8) {
        #pragma unroll
        for (int r = 0; r < 4; ++r)
          qn[(dtile * 16 + qd * 4 + r) * 8 + lm] = f2bf(acc[r]);
      }
    }
  }
}

// =================== K3a: x = mbar @ wvf^T (m97-structure, gload_lds) =======
__global__ __launch_bounds__(512, 1)
void tgat_xgemm(const unsigned short* __restrict__ ws,
                const unsigned short* __restrict__ qkm, float* __restrict__ xacc)
{
  __shared__ alignas(16) unsigned short sA[2][128 * 128];  // 64 KB
  __shared__ alignas(16) unsigned short sB[2][80 * 128];   // 40 KB
  const int tid = threadIdx.x, wid = tid >> 6, lane = tid & 63;
  const int qd = lane >> 4, lm = lane & 15;
  const int xcd = blockIdx.x & 7, j = blockIdx.x >> 3;
  const int nb = j & 3, mb = xcd + 8 * (j >> 2);
  const int n0 = mb * 128, c0 = nb * 80;
  const unsigned short* wvf = ws + WS_WVF;

  const int rhi = lane >> 4, blo = lane & 15;

  #define STAGE(kc, buf) {                                                     \
    for (int ri = wid; ri < 52; ri += 8) {                                     \
      if (ri < 32) {                                                           \
        int r = ri * 4 + rhi;                                                  \
        int blk = blo ^ (r & 7);                                               \
        GLDS(qkm + (size_t)(n0 + r) * 2560 + (kc) * 128 + blk * 8,             \
             &sA[buf][ri * 512]);                                              \
      } else {                                                                 \
        int jb = ri - 32;                                                      \
        int r = jb * 4 + rhi;                                                  \
        int blk = blo ^ (r & 7);                                               \
        GLDS(wvf + (size_t)(c0 + r) * 2560 + (kc) * 128 + blk * 8,             \
             &sB[buf][jb * 512]);                                              \
      }                                                                        \
    } }

  f32x4 acc[5] = {};
  STAGE(0, 0);
  __syncthreads();

  for (int c = 0; c < 20; ++c) {
    if (c < 19) STAGE(c + 1, (c + 1) & 1);      // issue-early into other buffer
    const unsigned short* Ab = sA[c & 1];
    const unsigned short* Bb = sB[c & 1];
    const int s = lm & 7;
    #pragma unroll
    for (int kt = 0; kt < 4; ++kt) {
      const int blk = ((kt << 2) | qd) ^ s;
      bf16x8 a = *(const bf16x8*)&Ab[(wid * 16 + lm) * 128 + blk * 8];
      #pragma unroll
      for (int u = 0; u < 5; ++u) {
        bf16x8 b = *(const bf16x8*)&Bb[(u * 16 + lm) * 128 + blk * 8];
        acc[u] = MFMA16(a, b, acc[u]);
      }
    }
    __syncthreads();                             // drains staging, frees buffer
  }

  #pragma unroll
  for (int u = 0; u < 5; ++u)
    #pragma unroll
    for (int r = 0; r < 4; ++r)
      xacc[(size_t)(n0 + wid * 16 + qd * 4 + r) * 320 + c0 + u * 16 + lm] = acc[u][r];
  #undef STAGE
}

// =================== K3b: LN + out GEMM (512 blocks) ========================
__global__ __launch_bounds__(256, 4)
void tgat_post2(const float* __restrict__ nf, const unsigned short* __restrict__ ws,
                const float* __restrict__ xacc, float* __restrict__ out)
{
  __shared__ alignas(16) unsigned short sQb[16 * 136];
  __shared__ alignas(16) unsigned short sXb[16 * 328];
  const int tid = threadIdx.x, wid = tid >> 6, lane = tid & 63, qd = lane >> 4, lm = lane & 15;
  const int n0 = blockIdx.x * 16;
  const unsigned short* nwc = ws + WS_NWC;
  const float* f32r = (const float*)(ws + WS_F32);

  { // stage h_dst bf16
    int nn = tid >> 4, kk = (tid & 15) * 8;
    const float4* src = (const float4*)(nf + (size_t)(n0 + nn) * NODE_IN + kk);
    float4 f0 = src[0], f1 = src[1];
    float v8[8] = {f0.x, f0.y, f0.z, f0.w, f1.x, f1.y, f1.z, f1.w};
    *(bf16x8*)&sQb[nn * 136 + kk] = pack8(v8);
  }
  // LN: thread owns (row rr, cols cl+16u); reduce over the 16-lane row group
  const int rr = tid >> 4, cl = tid & 15;
  float v[20], s1 = 0.f, s2 = 0.f;
  #pragma unroll
  for (int u = 0; u < 20; ++u) {
    int c = u * 16 + cl;
    float x = xacc[(size_t)(n0 + rr) * 320 + c] + f32r[F_CC + c];
    if (c < 128) x += nf[(size_t)(n0 + rr) * NODE_IN + c];
    v[u] = x; s1 += x; s2 += x * x;
  }
  #pragma unroll
  for (int off = 8; off >= 1; off >>= 1) { s1 += __shfl_xor(s1, off); s2 += __shfl_xor(s2, off); }
  float mean = s1 * (1.f / D_MODEL);
  float var  = s2 * (1.f / D_MODEL) - mean * mean;
  float rstd = rsqrtf(var + 1e-5f);
  #pragma unroll
  for (int u = 0; u < 20; ++u) {
    int c = u * 16 + cl;
    sXb[rr * 328 + c] = f2bf((v[u] - mean) * rstd);
  }
  __syncthreads();

  // out GEMM: M=16, N=128, K=448; 4 waves x 2 o-tiles
  #pragma unroll
  for (int t = 0; t < 2; ++t) {
    int o = (wid * 2 + t) * 16 + lm;
    f32x4 acc = {};
    for (int kt = 0; kt < 14; ++kt) {
      bf16x8 a;
      if (kt < 4) a = *(const bf16x8*)&sQb[lm * 136 + kt * 32 + qd * 8];
      else        a = *(const bf16x8*)&sXb[lm * 328 + (kt - 4) * 32 + qd * 8];
      bf16x8 b = *(const bf16x8*)&nwc[(size_t)o * IN2 + kt * 32 + qd * 8];
      acc = MFMA16(a, b, acc);
    }
    float bz = f32r[F_B2 + o];
    #pragma unroll
    for (int r = 0; r < 4; ++r)
      out[(size_t)(n0 + qd * 4 + r) * HID + o] = fmaxf(acc[r] + bz, 0.f);
  }
}

extern "C" void kernel_launch(void* const* d_in, const int* in_sizes, int n_in,
                              void* d_out, int out_size, void* d_ws, size_t ws_size,
                              hipStream_t stream) {
  const float* nf   = (const float*)d_in[0];
  const float* ef   = (const float*)d_in[1];
  const float* dtp  = (const float*)d_in[2];
  const int*   nidx = (const int*)  d_in[3];
  const float* freq = (const float*)d_in[4];
  const float* ph   = (const float*)d_in[5];
  const float* wq   = (const float*)d_in[6];
  const float* wk   = (const float*)d_in[7];
  const float* wv   = (const float*)d_in[8];
  const float* fcw  = (const float*)d_in[9];
  const float* fcb  = (const float*)d_in[10];
  const float* lng  = (const float*)d_in[11];
  const float* lnb_ = (const float*)d_in[12];
  const float* nw   = (const float*)d_in[13];
  const float* nb   = (const float*)d_in[14];
  float* out = (float*)d_out;
  unsigned short* ws = (unsigned short*)d_ws;
  unsigned short* qkm = ws + WS_QKM;
  float* xacc = (float*)(ws + WS_X);

  prep_all<<<1266, 256, 0, stream>>>(nw, lng, fcb, ph, wq, lnb_, nb, wk, fcw, wv, ws);
  prep_c0k<<<640, 256, 0, stream>>>(wk, ws);
  tgat_qk   <<<2560, 256, 0, stream>>>(nf, ws, qkm);
  tgat_attn <<<8192, 256, 0, stream>>>(nf, ef, dtp, nidx, freq, ph, qkm);
  tgat_xgemm<<<256,  512, 0, stream>>>(ws, qkm, xacc);
  tgat_post2<<<512,  256, 0, stream>>>(nf, ws, xacc, out);
}